// Round 8
// baseline (6677.553 us; speedup 1.0000x reference)
//
#include <hip/hip_runtime.h>
#include <hip/hip_bf16.h>

#define HEADS 4
#define DHEAD 64
#define CC 128
#define NPOS 2560
#define NB 2

// workspace element layout (shorts): xn | q | k | v | o
#define XN_ELE  ((size_t)NB * NPOS * CC)             // 655360
#define QKV_ELE ((size_t)NB * HEADS * NPOS * DHEAD)  // 1310720
#define WS_TOTAL (XN_ELE + 4 * QKV_ELE)              // 5898240 shorts = 11.25 MiB

static __device__ __forceinline__ float b2f(short u) {
    union { unsigned int i; float f; } v;
    v.i = ((unsigned int)(unsigned short)u) << 16;
    return v.f;
}
static __device__ __forceinline__ short f2b(float f) {
    __hip_bfloat16 h = __float2bfloat16(f);
    union { __hip_bfloat16 h; unsigned short u; } v; v.h = h;
    return (short)v.u;
}

// -------- Kernel 1 (NAIVE): channel LayerNorm, one thread per (b, n) --------
__global__ __launch_bounds__(256) void ln_naive(
    const float* __restrict__ x, const float* __restrict__ g,
    const float* __restrict__ bb, short* __restrict__ xn) {
    int i = blockIdx.x * 256 + threadIdx.x;      // 0 .. NB*NPOS-1
    if (i >= NB * NPOS) return;
    int b = i / NPOS, n = i % NPOS;
    float s = 0.f, sq = 0.f;
    for (int c = 0; c < CC; c++) {
        float v = x[(size_t)(b * CC + c) * NPOS + n];
        s += v; sq += v * v;
    }
    float mean = s * (1.f / CC);
    float var = fmaxf(sq * (1.f / CC) - mean * mean, 0.f);
    float inv = 1.f / (sqrtf(var) + 1e-5f);
    for (int c = 0; c < CC; c++) {
        float v = (x[(size_t)(b * CC + c) * NPOS + n] - mean) * inv * g[c] + bb[c];
        xn[((size_t)b * NPOS + n) * CC + c] = f2b(v);
    }
}

// -------- Kernel 2 (NAIVE): QKV projection, one output element per thread --------
__global__ __launch_bounds__(256) void qkv_naive(
    const float* __restrict__ w, const short* __restrict__ xn,
    short* __restrict__ q_ws, short* __restrict__ k_ws, short* __restrict__ v_ws) {
    int pos = blockIdx.x * 256 + threadIdx.x;   // 0..2559
    int orow = blockIdx.y;                      // 0..767
    int b = blockIdx.z;                         // 0..1
    float s = 0.f;
    for (int c = 0; c < CC; c++)
        s += b2f(f2b(w[(size_t)orow * CC + c])) * b2f(xn[((size_t)(b * NPOS) + pos) * CC + c]);
    int sec = orow >> 8, oi = orow & 255, h = oi >> 6, d = oi & 63;
    size_t bh = (size_t)(b * HEADS + h);
    if (sec == 0)      q_ws[(bh * NPOS + pos) * DHEAD + d] = f2b(s * 0.125f);
    else if (sec == 1) k_ws[(bh * NPOS + pos) * DHEAD + d] = f2b(s);
    else               v_ws[(bh * DHEAD + d) * NPOS + pos] = f2b(s);
}

// -------- Kernel 3 (NAIVE): attention, one q-row per thread, two-pass softmax --------
__global__ __launch_bounds__(256) void attn_naive(
    const short* __restrict__ q_ws, const short* __restrict__ k_ws,
    const short* __restrict__ v_ws, short* __restrict__ o_ws) {
    int qpos = blockIdx.x * 256 + threadIdx.x;  // 0..2559
    int bh = blockIdx.y;                        // 0..7
    float q[64];
    #pragma unroll
    for (int d = 0; d < 64; d++) q[d] = b2f(q_ws[((size_t)bh * NPOS + qpos) * DHEAD + d]);
    float m = -1e30f;
    for (int j = 0; j < NPOS; j++) {
        float s = 0.f;
        #pragma unroll
        for (int d = 0; d < 64; d++) s += q[d] * b2f(k_ws[((size_t)bh * NPOS + j) * DHEAD + d]);
        m = fmaxf(m, s);
    }
    float sum = 0.f;
    float o[64];
    #pragma unroll
    for (int d = 0; d < 64; d++) o[d] = 0.f;
    for (int j = 0; j < NPOS; j++) {
        float s = 0.f;
        #pragma unroll
        for (int d = 0; d < 64; d++) s += q[d] * b2f(k_ws[((size_t)bh * NPOS + j) * DHEAD + d]);
        float e = __expf(s - m);
        sum += e;
        #pragma unroll
        for (int d = 0; d < 64; d++) o[d] += e * b2f(v_ws[((size_t)(bh * DHEAD + d)) * NPOS + j]);
    }
    float inv = 1.f / sum;
    int b = bh >> 2, h = bh & 3;
    #pragma unroll
    for (int d = 0; d < 64; d++)
        o_ws[((size_t)(b * NPOS) + qpos) * 256 + h * DHEAD + d] = f2b(o[d] * inv);
}

// -------- Kernel 4 (NAIVE): output projection + bias, FLOAT32 output --------
__global__ __launch_bounds__(256) void proj_naive(
    const float* __restrict__ w_out, const float* __restrict__ b_out,
    const short* __restrict__ o_ws, float* __restrict__ out) {
    int pos = blockIdx.x * 256 + threadIdx.x;   // 0..2559
    int c = blockIdx.y;                         // 0..127
    int b = blockIdx.z;                         // 0..1
    float s = b_out[c];
    for (int k = 0; k < 256; k++)
        s += b2f(f2b(w_out[(size_t)c * 256 + k])) * b2f(o_ws[((size_t)(b * NPOS) + pos) * 256 + k]);
    if (!(fabsf(s) < 1e30f)) s = 1000.0f;       // non-finite tripwire
    out[((size_t)(b * CC) + c) * NPOS + pos] = s;   // f32 store (output dtype = float32)
}

extern "C" void kernel_launch(void* const* d_in, const int* in_sizes, int n_in,
                              void* d_out, int out_size, void* d_ws, size_t ws_size,
                              hipStream_t stream) {
    const float* x     = (const float*)d_in[0];
    const float* g     = (const float*)d_in[1];
    const float* b     = (const float*)d_in[2];
    const float* w_qkv = (const float*)d_in[3];
    const float* w_out = (const float*)d_in[4];
    const float* b_out = (const float*)d_in[5];
    float* out = (float*)d_out;   // FLOAT32 output (reference output dtype; out_npz=2.17MB ⇒ f32)

    const size_t out_bytes = (size_t)out_size * sizeof(float);
    const size_t ws_need   = WS_TOTAL * sizeof(short);

    // --- Tripwire A: input ordering/sizes signature ---
    {
        const int exp_sizes[6] = {655360, 128, 128, 98304, 32768, 128};
        int bad = -1;
        if (n_in != 6) bad = 15;
        else for (int i = 0; i < 6; i++) if (in_sizes[i] != exp_sizes[i]) { bad = i; break; }
        if (bad >= 0) {
            hipMemsetAsync(d_out, 0x50 | bad, out_bytes, stream);
            return;
        }
    }
    // --- Tripwire B: workspace size ---
    if (ws_size < ws_need) {
        int mb = (int)(ws_size >> 20); if (mb > 15) mb = 15;
        hipMemsetAsync(d_out, 0x40 | mb, out_bytes, stream);
        return;
    }

    short* xn   = (short*)d_ws;
    short* q_ws = xn + XN_ELE;
    short* k_ws = q_ws + QKV_ELE;
    short* v_ws = k_ws + QKV_ELE;
    short* o_ws = v_ws + QKV_ELE;

    (void)hipGetLastError();
    ln_naive<<<dim3((NB * NPOS + 255) / 256), 256, 0, stream>>>(x, g, b, xn);
    qkv_naive<<<dim3(NPOS / 256, 768, NB), 256, 0, stream>>>(w_qkv, xn, q_ws, k_ws, v_ws);
    attn_naive<<<dim3(NPOS / 256, NB * HEADS), 256, 0, stream>>>(q_ws, k_ws, v_ws, o_ws);
    proj_naive<<<dim3(NPOS / 256, CC, NB), 256, 0, stream>>>(w_out, b_out, o_ws, out);
    // --- Tripwire C: launch failure flood ---
    if (hipGetLastError() != hipSuccess) {
        hipMemsetAsync(d_out, 0xF0, out_bytes, stream);
    }
}

// Round 9
// 178.778 us; speedup vs baseline: 37.3511x; 37.3511x over previous
//
#include <hip/hip_runtime.h>
#include <hip/hip_bf16.h>

#define HEADS 4
#define DHEAD 64
#define CC 128
#define NPOS 2560
#define NB 2

// workspace element layout (shorts): xn | q | k | v | o
#define XN_ELE  ((size_t)NB * NPOS * CC)             // 655360
#define QKV_ELE ((size_t)NB * HEADS * NPOS * DHEAD)  // 1310720
#define WS_TOTAL (XN_ELE + 4 * QKV_ELE)              // 5898240 shorts = 11.25 MiB

typedef __attribute__((ext_vector_type(8))) short short8;
typedef __attribute__((ext_vector_type(4))) short short4_t;
typedef __attribute__((ext_vector_type(4))) float f32x4;

static __device__ __forceinline__ float b2f(short u) {
    union { unsigned int i; float f; } v;
    v.i = ((unsigned int)(unsigned short)u) << 16;
    return v.f;
}
static __device__ __forceinline__ short f2b(float f) {
    __hip_bfloat16 h = __float2bfloat16(f);
    union { __hip_bfloat16 h; unsigned short u; } v; v.h = h;
    return (short)v.u;
}

// -------- Kernel 1: channel LayerNorm (f32 in) -> xn transposed (b, pos, c) bf16 --------
__global__ __launch_bounds__(256) void ln_kernel(
    const float* __restrict__ x, const float* __restrict__ g,
    const float* __restrict__ bb, short* __restrict__ xn) {
    int p0 = blockIdx.x * 64, b = blockIdx.y;
    __shared__ float tile[128][65];
    __shared__ float redsum[4][64], redsq[4][64], meanS[64], invS[64];
    int t = threadIdx.x, p = t & 63, cpart = t >> 6;
    float s = 0.f, sq = 0.f;
    for (int k = 0; k < 32; k++) {
        int c = cpart * 32 + k;
        float v = x[((b * CC + c) * NPOS) + p0 + p];
        tile[c][p] = v;
        s += v; sq += v * v;
    }
    redsum[cpart][p] = s; redsq[cpart][p] = sq;
    __syncthreads();
    if (t < 64) {
        float S = redsum[0][t] + redsum[1][t] + redsum[2][t] + redsum[3][t];
        float Q = redsq[0][t] + redsq[1][t] + redsq[2][t] + redsq[3][t];
        float mean = S * (1.f / CC);
        float var = fmaxf(Q * (1.f / CC) - mean * mean, 0.f);
        meanS[t] = mean;
        invS[t] = 1.f / (sqrtf(var) + 1e-5f);
    }
    __syncthreads();
    for (int k = 0; k < 32; k++) {
        int idx = k * 256 + t;
        int c = idx & 127, pp = idx >> 7;
        float v = (tile[c][pp] - meanS[pp]) * invS[pp] * g[c] + bb[c];
        xn[((size_t)(b * NPOS) + p0 + pp) * CC + c] = f2b(v);
    }
}

// -------- Kernel 2: QKV projection (w f32). q:(bh,pos,d) scaled, k:(bh,pos,d), v:(bh,d,pos) --------
__global__ __launch_bounds__(256) void qkv_kernel(
    const float* __restrict__ w, const short* __restrict__ xn,
    short* __restrict__ q_ws, short* __restrict__ k_ws, short* __restrict__ v_ws) {
    int pt = blockIdx.x, ot = blockIdx.y, b = blockIdx.z;
    int p0 = pt * 64, o0 = ot * 64;
    __shared__ short Ws[64][136];
    __shared__ short Xs[64][136];
    int t = threadIdx.x, wv = t >> 6, l = t & 63;
    for (int i = 0; i < 8; i++) {
        int gidx = i * 256 + t;
        int r = gidx >> 5, cg = gidx & 31;
        f32x4 wv4 = *(const f32x4*)&w[(size_t)(o0 + r) * CC + cg * 4];
        short4_t sv = { f2b(wv4[0]), f2b(wv4[1]), f2b(wv4[2]), f2b(wv4[3]) };
        *(short4_t*)&Ws[r][cg * 4] = sv;
    }
    for (int i = 0; i < 4; i++) {
        int idx = i * 256 + t;
        int r = idx >> 4, ch = idx & 15;
        *(short8*)&Xs[r][ch * 8] = *(const short8*)&xn[((size_t)(b * NPOS) + p0 + r) * CC + ch * 8];
    }
    __syncthreads();
    f32x4 acc[4] = {{0,0,0,0},{0,0,0,0},{0,0,0,0},{0,0,0,0}};
    int lr = l & 15, lg = l >> 4;
    for (int kk = 0; kk < 4; kk++) {
        short8 a = *(short8*)&Ws[wv * 16 + lr][kk * 32 + lg * 8];
        for (int fb = 0; fb < 4; fb++) {
            short8 bf = *(short8*)&Xs[fb * 16 + lr][kk * 32 + lg * 8];
            acc[fb] = __builtin_amdgcn_mfma_f32_16x16x32_bf16(a, bf, acc[fb], 0, 0, 0);
        }
    }
    for (int fb = 0; fb < 4; fb++) {
        for (int r = 0; r < 4; r++) {
            int orow = o0 + wv * 16 + lg * 4 + r;
            int pos = p0 + fb * 16 + lr;
            float v = acc[fb][r];
            int sec = orow >> 8;
            int oi = orow & 255, h = oi >> 6, d = oi & 63;
            size_t bh = (size_t)(b * HEADS + h);
            if (sec == 0)      q_ws[(bh * NPOS + pos) * DHEAD + d] = f2b(v * 0.125f);
            else if (sec == 1) k_ws[(bh * NPOS + pos) * DHEAD + d] = f2b(v);
            else               v_ws[(bh * DHEAD + d) * NPOS + pos] = f2b(v);
        }
    }
}

// -------- Kernel 3: flash attention (bf16 ws). o_ws: (b, pos, h*64+d) bf16 --------
__global__ __launch_bounds__(256) void attn_kernel(
    const short* __restrict__ q_ws, const short* __restrict__ k_ws,
    const short* __restrict__ v_ws, short* __restrict__ o_ws) {
    int qt = blockIdx.x, bh = blockIdx.y;
    int q0 = qt * 64;
    __shared__ short Qs[64][72];
    __shared__ short Ks[64][72];
    __shared__ short Vs[64][72];
    __shared__ short Ps[64][72];
    int t = threadIdx.x, wv = t >> 6, l = t & 63;
    int lr = l & 15, lg = l >> 4;
    for (int i = 0; i < 2; i++) {
        int idx = i * 256 + t;
        int r = idx >> 3, ch = idx & 7;
        *(short8*)&Qs[r][ch * 8] = *(const short8*)&q_ws[((size_t)bh * NPOS + q0 + r) * DHEAD + ch * 8];
    }
    float m_[4], l_[4];
    f32x4 acc[4] = {{0,0,0,0},{0,0,0,0},{0,0,0,0},{0,0,0,0}};
    for (int r = 0; r < 4; r++) { m_[r] = -1e9f; l_[r] = 0.f; }
    for (int kt = 0; kt < NPOS / 64; kt++) {
        __syncthreads();
        for (int i = 0; i < 2; i++) {
            int idx = i * 256 + t;
            int r = idx >> 3, ch = idx & 7;
            *(short8*)&Ks[r][ch * 8] = *(const short8*)&k_ws[((size_t)bh * NPOS + kt * 64 + r) * DHEAD + ch * 8];
            *(short8*)&Vs[r][ch * 8] = *(const short8*)&v_ws[((size_t)bh * DHEAD + r) * NPOS + kt * 64 + ch * 8];
        }
        __syncthreads();
        f32x4 sf[4] = {{0,0,0,0},{0,0,0,0},{0,0,0,0},{0,0,0,0}};
        for (int kk = 0; kk < 2; kk++) {
            short8 a = *(short8*)&Qs[wv * 16 + lr][kk * 32 + lg * 8];
            for (int fb = 0; fb < 4; fb++) {
                short8 kb = *(short8*)&Ks[fb * 16 + lr][kk * 32 + lg * 8];
                sf[fb] = __builtin_amdgcn_mfma_f32_16x16x32_bf16(a, kb, sf[fb], 0, 0, 0);
            }
        }
        for (int r = 0; r < 4; r++) {
            float mx = fmaxf(fmaxf(sf[0][r], sf[1][r]), fmaxf(sf[2][r], sf[3][r]));
            for (int off = 1; off < 16; off <<= 1) mx = fmaxf(mx, __shfl_xor(mx, off, 64));
            float nm = fmaxf(m_[r], mx);
            float alpha = __expf(m_[r] - nm);
            float ps[4], rs = 0.f;
            for (int fb = 0; fb < 4; fb++) { ps[fb] = __expf(sf[fb][r] - nm); rs += ps[fb]; }
            for (int off = 1; off < 16; off <<= 1) rs += __shfl_xor(rs, off, 64);
            l_[r] = l_[r] * alpha + rs;
            m_[r] = nm;
            for (int fb = 0; fb < 4; fb++) {
                acc[fb][r] *= alpha;
                Ps[wv * 16 + lg * 4 + r][fb * 16 + lr] = f2b(ps[fb]);
            }
        }
        __syncthreads();   // fence Ps stores vs vector reads
        for (int kk = 0; kk < 2; kk++) {
            short8 pa = *(short8*)&Ps[wv * 16 + lr][kk * 32 + lg * 8];
            for (int fb = 0; fb < 4; fb++) {
                short8 vb = *(short8*)&Vs[fb * 16 + lr][kk * 32 + lg * 8];
                acc[fb] = __builtin_amdgcn_mfma_f32_16x16x32_bf16(pa, vb, acc[fb], 0, 0, 0);
            }
        }
    }
    int h = bh & (HEADS - 1), b = bh >> 2;
    for (int r = 0; r < 4; r++) {
        float inv = 1.f / l_[r];
        int pos = q0 + wv * 16 + lg * 4 + r;
        for (int fb = 0; fb < 4; fb++) {
            o_ws[((size_t)(b * NPOS) + pos) * 256 + h * DHEAD + fb * 16 + lr] = f2b(acc[fb][r] * inv);
        }
    }
}

// -------- Kernel 4: output projection (w_out f32) + bias -> FLOAT32 out --------
__global__ __launch_bounds__(256) void proj_kernel(
    const float* __restrict__ w_out, const float* __restrict__ b_out,
    const short* __restrict__ o_ws, float* __restrict__ out) {
    int pt = blockIdx.x, ct = blockIdx.y, b = blockIdx.z;
    int p0 = pt * 64, c0 = ct * 64;
    __shared__ short Ws[64][72];
    __shared__ short Os[64][72];
    int t = threadIdx.x, wv = t >> 6, l = t & 63;
    int lr = l & 15, lg = l >> 4;
    f32x4 acc[4] = {{0,0,0,0},{0,0,0,0},{0,0,0,0},{0,0,0,0}};
    for (int kc = 0; kc < 4; kc++) {
        __syncthreads();
        for (int i = 0; i < 4; i++) {
            int gidx = i * 256 + t;
            int r = gidx >> 4, cg = gidx & 15;
            f32x4 wv4 = *(const f32x4*)&w_out[(size_t)(c0 + r) * 256 + kc * 64 + cg * 4];
            short4_t sv = { f2b(wv4[0]), f2b(wv4[1]), f2b(wv4[2]), f2b(wv4[3]) };
            *(short4_t*)&Ws[r][cg * 4] = sv;
        }
        for (int i = 0; i < 2; i++) {
            int idx = i * 256 + t;
            int r = idx >> 3, ch = idx & 7;
            *(short8*)&Os[r][ch * 8] = *(const short8*)&o_ws[((size_t)(b * NPOS) + p0 + r) * 256 + kc * 64 + ch * 8];
        }
        __syncthreads();
        for (int kk = 0; kk < 2; kk++) {
            short8 a = *(short8*)&Ws[wv * 16 + lr][kk * 32 + lg * 8];
            for (int fb = 0; fb < 4; fb++) {
                short8 ob = *(short8*)&Os[fb * 16 + lr][kk * 32 + lg * 8];
                acc[fb] = __builtin_amdgcn_mfma_f32_16x16x32_bf16(a, ob, acc[fb], 0, 0, 0);
            }
        }
    }
    for (int r = 0; r < 4; r++) {
        int c = c0 + wv * 16 + lg * 4 + r;
        float bias = b_out[c];
        for (int fb = 0; fb < 4; fb++) {
            float vv = acc[fb][r] + bias;
            out[((size_t)(b * CC) + c) * NPOS + p0 + fb * 16 + lr] = vv;   // f32 store
        }
    }
}

extern "C" void kernel_launch(void* const* d_in, const int* in_sizes, int n_in,
                              void* d_out, int out_size, void* d_ws, size_t ws_size,
                              hipStream_t stream) {
    const float* x     = (const float*)d_in[0];
    const float* g     = (const float*)d_in[1];
    const float* b     = (const float*)d_in[2];
    const float* w_qkv = (const float*)d_in[3];
    const float* w_out = (const float*)d_in[4];
    const float* b_out = (const float*)d_in[5];
    float* out = (float*)d_out;   // FLOAT32 output (verified R8)

    const size_t out_bytes = (size_t)out_size * sizeof(float);
    const size_t ws_need   = WS_TOTAL * sizeof(short);

    {   // Tripwire A: input ordering/sizes signature
        const int exp_sizes[6] = {655360, 128, 128, 98304, 32768, 128};
        int bad = -1;
        if (n_in != 6) bad = 15;
        else for (int i = 0; i < 6; i++) if (in_sizes[i] != exp_sizes[i]) { bad = i; break; }
        if (bad >= 0) { hipMemsetAsync(d_out, 0x50 | bad, out_bytes, stream); return; }
    }
    if (ws_size < ws_need) {   // Tripwire B: workspace size
        int mb = (int)(ws_size >> 20); if (mb > 15) mb = 15;
        hipMemsetAsync(d_out, 0x40 | mb, out_bytes, stream);
        return;
    }

    short* xn   = (short*)d_ws;
    short* q_ws = xn + XN_ELE;
    short* k_ws = q_ws + QKV_ELE;
    short* v_ws = k_ws + QKV_ELE;
    short* o_ws = v_ws + QKV_ELE;

    (void)hipGetLastError();
    ln_kernel<<<dim3(NPOS / 64, NB), 256, 0, stream>>>(x, g, b, xn);
    qkv_kernel<<<dim3(NPOS / 64, 12, NB), 256, 0, stream>>>(w_qkv, xn, q_ws, k_ws, v_ws);
    attn_kernel<<<dim3(NPOS / 64, NB * HEADS), 256, 0, stream>>>(q_ws, k_ws, v_ws, o_ws);
    proj_kernel<<<dim3(NPOS / 64, 2, NB), 256, 0, stream>>>(w_out, b_out, o_ws, out);
    if (hipGetLastError() != hipSuccess) {   // Tripwire C: launch failure flood
        hipMemsetAsync(d_out, 0xF0, out_bytes, stream);
    }
}

// Round 10
// 167.917 us; speedup vs baseline: 39.7669x; 1.0647x over previous
//
#include <hip/hip_runtime.h>
#include <hip/hip_bf16.h>

#define HEADS 4
#define DHEAD 64
#define CC 128
#define NPOS 2560
#define NB 2

// workspace element layout (shorts): xn | q | k | v | o
#define XN_ELE  ((size_t)NB * NPOS * CC)             // 655360
#define QKV_ELE ((size_t)NB * HEADS * NPOS * DHEAD)  // 1310720
#define WS_TOTAL (XN_ELE + 4 * QKV_ELE)              // 5898240 shorts = 11.25 MiB

typedef __attribute__((ext_vector_type(8))) short short8;
typedef __attribute__((ext_vector_type(4))) short short4_t;
typedef __attribute__((ext_vector_type(4))) float f32x4;

static __device__ __forceinline__ float b2f(short u) {
    union { unsigned int i; float f; } v;
    v.i = ((unsigned int)(unsigned short)u) << 16;
    return v.f;
}
static __device__ __forceinline__ short f2b(float f) {
    __hip_bfloat16 h = __float2bfloat16(f);
    union { __hip_bfloat16 h; unsigned short u; } v; v.h = h;
    return (short)v.u;
}

// -------- Kernel 1: channel LayerNorm (f32 in) -> xn transposed (b, pos, c) bf16 --------
__global__ __launch_bounds__(256) void ln_kernel(
    const float* __restrict__ x, const float* __restrict__ g,
    const float* __restrict__ bb, short* __restrict__ xn) {
    int p0 = blockIdx.x * 64, b = blockIdx.y;
    __shared__ float tile[128][65];
    __shared__ float redsum[4][64], redsq[4][64], meanS[64], invS[64];
    int t = threadIdx.x, p = t & 63, cpart = t >> 6;
    float s = 0.f, sq = 0.f;
    for (int k = 0; k < 32; k++) {
        int c = cpart * 32 + k;
        float v = x[((b * CC + c) * NPOS) + p0 + p];
        tile[c][p] = v;
        s += v; sq += v * v;
    }
    redsum[cpart][p] = s; redsq[cpart][p] = sq;
    __syncthreads();
    if (t < 64) {
        float S = redsum[0][t] + redsum[1][t] + redsum[2][t] + redsum[3][t];
        float Q = redsq[0][t] + redsq[1][t] + redsq[2][t] + redsq[3][t];
        float mean = S * (1.f / CC);
        float var = fmaxf(Q * (1.f / CC) - mean * mean, 0.f);
        meanS[t] = mean;
        invS[t] = 1.f / (sqrtf(var) + 1e-5f);
    }
    __syncthreads();
    for (int k = 0; k < 32; k++) {
        int idx = k * 256 + t;
        int c = idx & 127, pp = idx >> 7;
        float v = (tile[c][pp] - meanS[pp]) * invS[pp] * g[c] + bb[c];
        xn[((size_t)(b * NPOS) + p0 + pp) * CC + c] = f2b(v);
    }
}

// -------- Kernel 2: QKV projection (w f32). q:(bh,pos,d) scaled, k:(bh,pos,d), v:(bh,d,pos) --------
__global__ __launch_bounds__(256) void qkv_kernel(
    const float* __restrict__ w, const short* __restrict__ xn,
    short* __restrict__ q_ws, short* __restrict__ k_ws, short* __restrict__ v_ws) {
    int pt = blockIdx.x, ot = blockIdx.y, b = blockIdx.z;
    int p0 = pt * 64, o0 = ot * 64;
    __shared__ short Ws[64][136];
    __shared__ short Xs[64][136];
    int t = threadIdx.x, wv = t >> 6, l = t & 63;
    for (int i = 0; i < 8; i++) {
        int gidx = i * 256 + t;
        int r = gidx >> 5, cg = gidx & 31;
        f32x4 wv4 = *(const f32x4*)&w[(size_t)(o0 + r) * CC + cg * 4];
        short4_t sv = { f2b(wv4[0]), f2b(wv4[1]), f2b(wv4[2]), f2b(wv4[3]) };
        *(short4_t*)&Ws[r][cg * 4] = sv;
    }
    for (int i = 0; i < 4; i++) {
        int idx = i * 256 + t;
        int r = idx >> 4, ch = idx & 15;
        *(short8*)&Xs[r][ch * 8] = *(const short8*)&xn[((size_t)(b * NPOS) + p0 + r) * CC + ch * 8];
    }
    __syncthreads();
    f32x4 acc[4] = {{0,0,0,0},{0,0,0,0},{0,0,0,0},{0,0,0,0}};
    int lr = l & 15, lg = l >> 4;
    for (int kk = 0; kk < 4; kk++) {
        short8 a = *(short8*)&Ws[wv * 16 + lr][kk * 32 + lg * 8];
        for (int fb = 0; fb < 4; fb++) {
            short8 bf = *(short8*)&Xs[fb * 16 + lr][kk * 32 + lg * 8];
            acc[fb] = __builtin_amdgcn_mfma_f32_16x16x32_bf16(a, bf, acc[fb], 0, 0, 0);
        }
    }
    for (int fb = 0; fb < 4; fb++) {
        for (int r = 0; r < 4; r++) {
            int orow = o0 + wv * 16 + lg * 4 + r;
            int pos = p0 + fb * 16 + lr;
            float v = acc[fb][r];
            int sec = orow >> 8;
            int oi = orow & 255, h = oi >> 6, d = oi & 63;
            size_t bh = (size_t)(b * HEADS + h);
            if (sec == 0)      q_ws[(bh * NPOS + pos) * DHEAD + d] = f2b(v * 0.125f);
            else if (sec == 1) k_ws[(bh * NPOS + pos) * DHEAD + d] = f2b(v);
            else               v_ws[(bh * DHEAD + d) * NPOS + pos] = f2b(v);
        }
    }
}

// -------- Kernel 3: flash attention, double-buffered K/V with register prefetch --------
// One __syncthreads per K-tile. Ps is wave-private (no barrier needed: lanes lockstep,
// compiler inserts lgkmcnt for same-array ds_write->ds_read).
__global__ __launch_bounds__(256) void attn_kernel(
    const short* __restrict__ q_ws, const short* __restrict__ k_ws,
    const short* __restrict__ v_ws, short* __restrict__ o_ws) {
    int qt = blockIdx.x, bh = blockIdx.y;
    int q0 = qt * 64;
    __shared__ short Qs[64][72];
    __shared__ short Ks[2][64][72];
    __shared__ short Vs[2][64][72];
    __shared__ short Ps[64][72];
    int t = threadIdx.x, wv = t >> 6, l = t & 63;
    int lr = l & 15, lg = l >> 4;
    int sr0 = t >> 3, sc = (t & 7) * 8;   // staging coords: rows sr0, sr0+32; 8-short col chunk
    int sr1 = sr0 + 32;
    const short* kbp = k_ws + (size_t)bh * NPOS * DHEAD;
    const short* vbp = v_ws + (size_t)bh * DHEAD * NPOS;

    // Prologue: stage Q and tile 0
    *(short8*)&Qs[sr0][sc] = *(const short8*)&q_ws[((size_t)bh * NPOS + q0 + sr0) * DHEAD + sc];
    *(short8*)&Qs[sr1][sc] = *(const short8*)&q_ws[((size_t)bh * NPOS + q0 + sr1) * DHEAD + sc];
    *(short8*)&Ks[0][sr0][sc] = *(const short8*)&kbp[(size_t)sr0 * DHEAD + sc];
    *(short8*)&Ks[0][sr1][sc] = *(const short8*)&kbp[(size_t)sr1 * DHEAD + sc];
    *(short8*)&Vs[0][sr0][sc] = *(const short8*)&vbp[(size_t)sr0 * NPOS + sc];
    *(short8*)&Vs[0][sr1][sc] = *(const short8*)&vbp[(size_t)sr1 * NPOS + sc];
    __syncthreads();

    float m_[4], l_[4];
    f32x4 acc[4] = {{0,0,0,0},{0,0,0,0},{0,0,0,0},{0,0,0,0}};
    for (int r = 0; r < 4; r++) { m_[r] = -1e9f; l_[r] = 0.f; }

    for (int kt = 0; kt < NPOS / 64; kt++) {
        int cur = kt & 1;
        bool pf = (kt + 1 < NPOS / 64);
        short8 kr0, kr1, vr0, vr1;
        if (pf) {  // issue next tile's loads; latency hides under compute below
            int koff = (kt + 1) * 64;
            kr0 = *(const short8*)&kbp[(size_t)(koff + sr0) * DHEAD + sc];
            kr1 = *(const short8*)&kbp[(size_t)(koff + sr1) * DHEAD + sc];
            vr0 = *(const short8*)&vbp[(size_t)sr0 * NPOS + koff + sc];
            vr1 = *(const short8*)&vbp[(size_t)sr1 * NPOS + koff + sc];
        }
        // QK^T
        f32x4 sf[4] = {{0,0,0,0},{0,0,0,0},{0,0,0,0},{0,0,0,0}};
        for (int kk = 0; kk < 2; kk++) {
            short8 a = *(short8*)&Qs[wv * 16 + lr][kk * 32 + lg * 8];
            for (int fb = 0; fb < 4; fb++) {
                short8 kb = *(short8*)&Ks[cur][fb * 16 + lr][kk * 32 + lg * 8];
                sf[fb] = __builtin_amdgcn_mfma_f32_16x16x32_bf16(a, kb, sf[fb], 0, 0, 0);
            }
        }
        // online softmax (wave-parallel, 16-lane butterflies per row)
        for (int r = 0; r < 4; r++) {
            float mx = fmaxf(fmaxf(sf[0][r], sf[1][r]), fmaxf(sf[2][r], sf[3][r]));
            for (int off = 1; off < 16; off <<= 1) mx = fmaxf(mx, __shfl_xor(mx, off, 64));
            float nm = fmaxf(m_[r], mx);
            float alpha = __expf(m_[r] - nm);
            float ps[4], rs = 0.f;
            for (int fb = 0; fb < 4; fb++) { ps[fb] = __expf(sf[fb][r] - nm); rs += ps[fb]; }
            for (int off = 1; off < 16; off <<= 1) rs += __shfl_xor(rs, off, 64);
            l_[r] = l_[r] * alpha + rs;
            m_[r] = nm;
            for (int fb = 0; fb < 4; fb++) {
                acc[fb][r] *= alpha;
                Ps[wv * 16 + lg * 4 + r][fb * 16 + lr] = f2b(ps[fb]);
            }
        }
        // PV (Ps rows are wave-private; intra-wave lgkmcnt ordering suffices)
        for (int kk = 0; kk < 2; kk++) {
            short8 pa = *(short8*)&Ps[wv * 16 + lr][kk * 32 + lg * 8];
            for (int fb = 0; fb < 4; fb++) {
                short8 vv = *(short8*)&Vs[cur][fb * 16 + lr][kk * 32 + lg * 8];
                acc[fb] = __builtin_amdgcn_mfma_f32_16x16x32_bf16(pa, vv, acc[fb], 0, 0, 0);
            }
        }
        // land prefetched tile into the alternate buffer (safe: last read of buf
        // cur^1 finished before the previous iteration's barrier)
        if (pf) {
            *(short8*)&Ks[cur ^ 1][sr0][sc] = kr0;
            *(short8*)&Ks[cur ^ 1][sr1][sc] = kr1;
            *(short8*)&Vs[cur ^ 1][sr0][sc] = vr0;
            *(short8*)&Vs[cur ^ 1][sr1][sc] = vr1;
        }
        __syncthreads();   // the single per-iteration barrier
    }

    int h = bh & (HEADS - 1), b = bh >> 2;
    for (int r = 0; r < 4; r++) {
        float inv = 1.f / l_[r];
        int pos = q0 + wv * 16 + lg * 4 + r;
        for (int fb = 0; fb < 4; fb++) {
            o_ws[((size_t)(b * NPOS) + pos) * 256 + h * DHEAD + fb * 16 + lr] = f2b(acc[fb][r] * inv);
        }
    }
}

// -------- Kernel 4: output projection (w_out f32) + bias -> FLOAT32 out --------
__global__ __launch_bounds__(256) void proj_kernel(
    const float* __restrict__ w_out, const float* __restrict__ b_out,
    const short* __restrict__ o_ws, float* __restrict__ out) {
    int pt = blockIdx.x, ct = blockIdx.y, b = blockIdx.z;
    int p0 = pt * 64, c0 = ct * 64;
    __shared__ short Ws[64][72];
    __shared__ short Os[64][72];
    int t = threadIdx.x, wv = t >> 6, l = t & 63;
    int lr = l & 15, lg = l >> 4;
    f32x4 acc[4] = {{0,0,0,0},{0,0,0,0},{0,0,0,0},{0,0,0,0}};
    for (int kc = 0; kc < 4; kc++) {
        __syncthreads();
        for (int i = 0; i < 4; i++) {
            int gidx = i * 256 + t;
            int r = gidx >> 4, cg = gidx & 15;
            f32x4 wv4 = *(const f32x4*)&w_out[(size_t)(c0 + r) * 256 + kc * 64 + cg * 4];
            short4_t sv = { f2b(wv4[0]), f2b(wv4[1]), f2b(wv4[2]), f2b(wv4[3]) };
            *(short4_t*)&Ws[r][cg * 4] = sv;
        }
        for (int i = 0; i < 2; i++) {
            int idx = i * 256 + t;
            int r = idx >> 3, ch = idx & 7;
            *(short8*)&Os[r][ch * 8] = *(const short8*)&o_ws[((size_t)(b * NPOS) + p0 + r) * 256 + kc * 64 + ch * 8];
        }
        __syncthreads();
        for (int kk = 0; kk < 2; kk++) {
            short8 a = *(short8*)&Ws[wv * 16 + lr][kk * 32 + lg * 8];
            for (int fb = 0; fb < 4; fb++) {
                short8 ob = *(short8*)&Os[fb * 16 + lr][kk * 32 + lg * 8];
                acc[fb] = __builtin_amdgcn_mfma_f32_16x16x32_bf16(a, ob, acc[fb], 0, 0, 0);
            }
        }
    }
    for (int r = 0; r < 4; r++) {
        int c = c0 + wv * 16 + lg * 4 + r;
        float bias = b_out[c];
        for (int fb = 0; fb < 4; fb++) {
            float vv = acc[fb][r] + bias;
            out[((size_t)(b * CC) + c) * NPOS + p0 + fb * 16 + lr] = vv;   // f32 store
        }
    }
}

extern "C" void kernel_launch(void* const* d_in, const int* in_sizes, int n_in,
                              void* d_out, int out_size, void* d_ws, size_t ws_size,
                              hipStream_t stream) {
    const float* x     = (const float*)d_in[0];
    const float* g     = (const float*)d_in[1];
    const float* b     = (const float*)d_in[2];
    const float* w_qkv = (const float*)d_in[3];
    const float* w_out = (const float*)d_in[4];
    const float* b_out = (const float*)d_in[5];
    float* out = (float*)d_out;   // FLOAT32 output (verified R8)

    const size_t out_bytes = (size_t)out_size * sizeof(float);
    const size_t ws_need   = WS_TOTAL * sizeof(short);

    {   // Tripwire A: input ordering/sizes signature
        const int exp_sizes[6] = {655360, 128, 128, 98304, 32768, 128};
        int bad = -1;
        if (n_in != 6) bad = 15;
        else for (int i = 0; i < 6; i++) if (in_sizes[i] != exp_sizes[i]) { bad = i; break; }
        if (bad >= 0) { hipMemsetAsync(d_out, 0x50 | bad, out_bytes, stream); return; }
    }
    if (ws_size < ws_need) {   // Tripwire B: workspace size
        int mb = (int)(ws_size >> 20); if (mb > 15) mb = 15;
        hipMemsetAsync(d_out, 0x40 | mb, out_bytes, stream);
        return;
    }

    short* xn   = (short*)d_ws;
    short* q_ws = xn + XN_ELE;
    short* k_ws = q_ws + QKV_ELE;
    short* v_ws = k_ws + QKV_ELE;
    short* o_ws = v_ws + QKV_ELE;

    (void)hipGetLastError();
    ln_kernel<<<dim3(NPOS / 64, NB), 256, 0, stream>>>(x, g, b, xn);
    qkv_kernel<<<dim3(NPOS / 64, 12, NB), 256, 0, stream>>>(w_qkv, xn, q_ws, k_ws, v_ws);
    attn_kernel<<<dim3(NPOS / 64, NB * HEADS), 256, 0, stream>>>(q_ws, k_ws, v_ws, o_ws);
    proj_kernel<<<dim3(NPOS / 64, 2, NB), 256, 0, stream>>>(w_out, b_out, o_ws, out);
    if (hipGetLastError() != hipSuccess) {   // Tripwire C: launch failure flood
        hipMemsetAsync(d_out, 0xF0, out_bytes, stream);
    }
}

// Round 11
// 135.197 us; speedup vs baseline: 49.3914x; 1.2420x over previous
//
#include <hip/hip_runtime.h>
#include <hip/hip_bf16.h>

#define HEADS 4
#define DHEAD 64
#define CC 128
#define NPOS 2560
#define NB 2

// workspace element layout (shorts): xn | q | k | v | o
#define XN_ELE  ((size_t)NB * NPOS * CC)             // 655360
#define QKV_ELE ((size_t)NB * HEADS * NPOS * DHEAD)  // 1310720
#define WS_TOTAL (XN_ELE + 4 * QKV_ELE)              // 5898240 shorts = 11.25 MiB

typedef __attribute__((ext_vector_type(8))) short short8;
typedef __attribute__((ext_vector_type(4))) short short4_t;
typedef __attribute__((ext_vector_type(4))) float f32x4;

// XOR-swizzled LDS index: 64-short (128B) rows, 16B-granule swizzle (T2).
#define SIDX(row, col) (((row) << 6) + ((col) ^ (((row) & 7) << 3)))

static __device__ __forceinline__ float b2f(short u) {
    union { unsigned int i; float f; } v;
    v.i = ((unsigned int)(unsigned short)u) << 16;
    return v.f;
}
static __device__ __forceinline__ short f2b(float f) {
    __hip_bfloat16 h = __float2bfloat16(f);
    union { __hip_bfloat16 h; unsigned short u; } v; v.h = h;
    return (short)v.u;
}

// -------- Kernel 1: channel LayerNorm (f32 in) -> xn transposed (b, pos, c) bf16 --------
__global__ __launch_bounds__(256) void ln_kernel(
    const float* __restrict__ x, const float* __restrict__ g,
    const float* __restrict__ bb, short* __restrict__ xn) {
    int p0 = blockIdx.x * 64, b = blockIdx.y;
    __shared__ float tile[128][65];
    __shared__ float redsum[4][64], redsq[4][64], meanS[64], invS[64];
    int t = threadIdx.x, p = t & 63, cpart = t >> 6;
    float s = 0.f, sq = 0.f;
    for (int k = 0; k < 32; k++) {
        int c = cpart * 32 + k;
        float v = x[((b * CC + c) * NPOS) + p0 + p];
        tile[c][p] = v;
        s += v; sq += v * v;
    }
    redsum[cpart][p] = s; redsq[cpart][p] = sq;
    __syncthreads();
    if (t < 64) {
        float S = redsum[0][t] + redsum[1][t] + redsum[2][t] + redsum[3][t];
        float Q = redsq[0][t] + redsq[1][t] + redsq[2][t] + redsq[3][t];
        float mean = S * (1.f / CC);
        float var = fmaxf(Q * (1.f / CC) - mean * mean, 0.f);
        meanS[t] = mean;
        invS[t] = 1.f / (sqrtf(var) + 1e-5f);
    }
    __syncthreads();
    for (int k = 0; k < 32; k++) {
        int idx = k * 256 + t;
        int c = idx & 127, pp = idx >> 7;
        float v = (tile[c][pp] - meanS[pp]) * invS[pp] * g[c] + bb[c];
        xn[((size_t)(b * NPOS) + p0 + pp) * CC + c] = f2b(v);
    }
}

// -------- Kernel 2: QKV projection (w f32). q:(bh,pos,d) scaled, k:(bh,pos,d), v:(bh,d,pos) --------
__global__ __launch_bounds__(256) void qkv_kernel(
    const float* __restrict__ w, const short* __restrict__ xn,
    short* __restrict__ q_ws, short* __restrict__ k_ws, short* __restrict__ v_ws) {
    int pt = blockIdx.x, ot = blockIdx.y, b = blockIdx.z;
    int p0 = pt * 64, o0 = ot * 64;
    __shared__ short Ws[64][136];
    __shared__ short Xs[64][136];
    int t = threadIdx.x, wv = t >> 6, l = t & 63;
    for (int i = 0; i < 8; i++) {
        int gidx = i * 256 + t;
        int r = gidx >> 5, cg = gidx & 31;
        f32x4 wv4 = *(const f32x4*)&w[(size_t)(o0 + r) * CC + cg * 4];
        short4_t sv = { f2b(wv4[0]), f2b(wv4[1]), f2b(wv4[2]), f2b(wv4[3]) };
        *(short4_t*)&Ws[r][cg * 4] = sv;
    }
    for (int i = 0; i < 4; i++) {
        int idx = i * 256 + t;
        int r = idx >> 4, ch = idx & 15;
        *(short8*)&Xs[r][ch * 8] = *(const short8*)&xn[((size_t)(b * NPOS) + p0 + r) * CC + ch * 8];
    }
    __syncthreads();
    f32x4 acc[4] = {{0,0,0,0},{0,0,0,0},{0,0,0,0},{0,0,0,0}};
    int lr = l & 15, lg = l >> 4;
    for (int kk = 0; kk < 4; kk++) {
        short8 a = *(short8*)&Ws[wv * 16 + lr][kk * 32 + lg * 8];
        for (int fb = 0; fb < 4; fb++) {
            short8 bf = *(short8*)&Xs[fb * 16 + lr][kk * 32 + lg * 8];
            acc[fb] = __builtin_amdgcn_mfma_f32_16x16x32_bf16(a, bf, acc[fb], 0, 0, 0);
        }
    }
    // packed stores: q/k pack 4 consecutive d (r=0..3) into one 8B store; v stays scalar
    int orow0 = o0 + wv * 16 + lg * 4;
    int sec = orow0 >> 8;
    int oi = orow0 & 255, h = oi >> 6, d0 = oi & 63;
    size_t bh = (size_t)(b * HEADS + h);
    for (int fb = 0; fb < 4; fb++) {
        int pos = p0 + fb * 16 + lr;
        if (sec == 0) {
            short4_t qv = { f2b(acc[fb][0] * 0.125f), f2b(acc[fb][1] * 0.125f),
                            f2b(acc[fb][2] * 0.125f), f2b(acc[fb][3] * 0.125f) };
            *(short4_t*)&q_ws[(bh * NPOS + pos) * DHEAD + d0] = qv;
        } else if (sec == 1) {
            short4_t kv = { f2b(acc[fb][0]), f2b(acc[fb][1]), f2b(acc[fb][2]), f2b(acc[fb][3]) };
            *(short4_t*)&k_ws[(bh * NPOS + pos) * DHEAD + d0] = kv;
        } else {
            for (int r = 0; r < 4; r++)
                v_ws[(bh * DHEAD + d0 + r) * NPOS + pos] = f2b(acc[fb][r]);
        }
    }
}

// -------- Kernel 3: flash attention, swapped-QK^T + XOR-swizzled LDS --------
// S^T = mfma(K,Q): lane holds 16 P values of q-row (wv*16+lr) -> in-lane softmax
// (2 shuffles). PV: O = mfma(V^T, P^T). One barrier/iter; K/V double-buffered.
__global__ __launch_bounds__(256) void attn_kernel(
    const short* __restrict__ q_ws, const short* __restrict__ k_ws,
    const short* __restrict__ v_ws, short* __restrict__ o_ws) {
    int qt = blockIdx.x, bh = blockIdx.y;
    int q0 = qt * 64;
    __shared__ short Ks[2][64 * 64];
    __shared__ short Vs[2][64 * 64];
    __shared__ short PsT[64 * 64];
    int t = threadIdx.x, wv = t >> 6, l = t & 63;
    int lr = l & 15, lg = l >> 4;
    int sr0 = t >> 3, sr1 = sr0 + 32, sc = (t & 7) * 8;
    const short* kbp = k_ws + (size_t)bh * NPOS * DHEAD;
    const short* vbp = v_ws + (size_t)bh * DHEAD * NPOS;

    // Q fragment lives in registers: B-operand rows = q-row wv*16+lr
    short8 qreg[2];
    for (int kk = 0; kk < 2; kk++)
        qreg[kk] = *(const short8*)&q_ws[((size_t)bh * NPOS + q0 + wv * 16 + lr) * DHEAD + kk * 32 + lg * 8];

    // Prologue: stage K/V tile 0 (swizzled)
    *(short8*)&Ks[0][SIDX(sr0, sc)] = *(const short8*)&kbp[(size_t)sr0 * DHEAD + sc];
    *(short8*)&Ks[0][SIDX(sr1, sc)] = *(const short8*)&kbp[(size_t)sr1 * DHEAD + sc];
    *(short8*)&Vs[0][SIDX(sr0, sc)] = *(const short8*)&vbp[(size_t)sr0 * NPOS + sc];
    *(short8*)&Vs[0][SIDX(sr1, sc)] = *(const short8*)&vbp[(size_t)sr1 * NPOS + sc];
    __syncthreads();

    float m_ = -1e9f, l_ = 0.f;
    f32x4 acc[4] = {{0,0,0,0},{0,0,0,0},{0,0,0,0},{0,0,0,0}};
    int prow = wv * 16 + lr;

    for (int kt = 0; kt < NPOS / 64; kt++) {
        int cur = kt & 1;
        bool pf = (kt + 1 < NPOS / 64);
        short8 kr0, kr1, vr0, vr1;
        if (pf) {
            int koff = (kt + 1) * 64;
            kr0 = *(const short8*)&kbp[(size_t)(koff + sr0) * DHEAD + sc];
            kr1 = *(const short8*)&kbp[(size_t)(koff + sr1) * DHEAD + sc];
            vr0 = *(const short8*)&vbp[(size_t)sr0 * NPOS + koff + sc];
            vr1 = *(const short8*)&vbp[(size_t)sr1 * NPOS + koff + sc];
        }
        // QK^T transposed: sf[fb] holds S^T[k=fb*16+lg*4+r][q=wv*16+lr]
        f32x4 sf[4] = {{0,0,0,0},{0,0,0,0},{0,0,0,0},{0,0,0,0}};
        #pragma unroll
        for (int kk = 0; kk < 2; kk++) {
            #pragma unroll
            for (int fb = 0; fb < 4; fb++) {
                short8 kb = *(short8*)&Ks[cur][SIDX(fb * 16 + lr, kk * 32 + lg * 8)];
                sf[fb] = __builtin_amdgcn_mfma_f32_16x16x32_bf16(kb, qreg[kk], sf[fb], 0, 0, 0);
            }
        }
        // in-lane softmax for row q=prow (16 values per lane; 4 lanes per row)
        float m0 = fmaxf(fmaxf(sf[0][0], sf[0][1]), fmaxf(sf[0][2], sf[0][3]));
        float m1 = fmaxf(fmaxf(sf[1][0], sf[1][1]), fmaxf(sf[1][2], sf[1][3]));
        float m2 = fmaxf(fmaxf(sf[2][0], sf[2][1]), fmaxf(sf[2][2], sf[2][3]));
        float m3 = fmaxf(fmaxf(sf[3][0], sf[3][1]), fmaxf(sf[3][2], sf[3][3]));
        float mx = fmaxf(fmaxf(m0, m1), fmaxf(m2, m3));
        mx = fmaxf(mx, __shfl_xor(mx, 16, 64));
        mx = fmaxf(mx, __shfl_xor(mx, 32, 64));
        float nm = fmaxf(m_, mx);
        float alpha = __expf(m_ - nm);
        float ps[4][4];
        float rs = 0.f;
        #pragma unroll
        for (int fb = 0; fb < 4; fb++) {
            float s0 = __expf(sf[fb][0] - nm), s1 = __expf(sf[fb][1] - nm);
            float s2 = __expf(sf[fb][2] - nm), s3 = __expf(sf[fb][3] - nm);
            ps[fb][0] = s0; ps[fb][1] = s1; ps[fb][2] = s2; ps[fb][3] = s3;
            rs += (s0 + s1) + (s2 + s3);
        }
        rs += __shfl_xor(rs, 16, 64);
        rs += __shfl_xor(rs, 32, 64);
        l_ = l_ * alpha + rs;
        m_ = nm;
        #pragma unroll
        for (int db = 0; db < 4; db++) {
            acc[db][0] *= alpha; acc[db][1] *= alpha;
            acc[db][2] *= alpha; acc[db][3] *= alpha;
        }
        // write P^T rows: lane owns 4x short4 chunks of row prow (k = fb*16+lg*4..+3)
        #pragma unroll
        for (int fb = 0; fb < 4; fb++) {
            short4_t pk = { f2b(ps[fb][0]), f2b(ps[fb][1]), f2b(ps[fb][2]), f2b(ps[fb][3]) };
            *(short4_t*)&PsT[SIDX(prow, fb * 16 + lg * 4)] = pk;
        }
        // PV: O[q][d] = mfma(A=Vs (V^T rows=d), B=PsT (rows=q)) summed over k
        #pragma unroll
        for (int kk = 0; kk < 2; kk++) {
            short8 pb = *(short8*)&PsT[SIDX(prow, kk * 32 + lg * 8)];
            #pragma unroll
            for (int db = 0; db < 4; db++) {
                short8 va = *(short8*)&Vs[cur][SIDX(db * 16 + lr, kk * 32 + lg * 8)];
                acc[db] = __builtin_amdgcn_mfma_f32_16x16x32_bf16(va, pb, acc[db], 0, 0, 0);
            }
        }
        // land prefetched tile into alternate buffer
        if (pf) {
            *(short8*)&Ks[cur ^ 1][SIDX(sr0, sc)] = kr0;
            *(short8*)&Ks[cur ^ 1][SIDX(sr1, sc)] = kr1;
            *(short8*)&Vs[cur ^ 1][SIDX(sr0, sc)] = vr0;
            *(short8*)&Vs[cur ^ 1][SIDX(sr1, sc)] = vr1;
        }
        __syncthreads();
    }

    int h = bh & (HEADS - 1), b = bh >> 2;
    float inv = 1.f / l_;
    int pos = q0 + prow;
    #pragma unroll
    for (int db = 0; db < 4; db++) {
        short4_t ov = { f2b(acc[db][0] * inv), f2b(acc[db][1] * inv),
                        f2b(acc[db][2] * inv), f2b(acc[db][3] * inv) };
        *(short4_t*)&o_ws[((size_t)(b * NPOS) + pos) * 256 + h * DHEAD + db * 16 + lg * 4] = ov;
    }
}

// -------- Kernel 4: output projection (w_out f32) + bias -> FLOAT32 out --------
__global__ __launch_bounds__(256) void proj_kernel(
    const float* __restrict__ w_out, const float* __restrict__ b_out,
    const short* __restrict__ o_ws, float* __restrict__ out) {
    int pt = blockIdx.x, ct = blockIdx.y, b = blockIdx.z;
    int p0 = pt * 64, c0 = ct * 64;
    __shared__ short Ws[64][72];
    __shared__ short Os[64][72];
    int t = threadIdx.x, wv = t >> 6, l = t & 63;
    int lr = l & 15, lg = l >> 4;
    f32x4 acc[4] = {{0,0,0,0},{0,0,0,0},{0,0,0,0},{0,0,0,0}};
    for (int kc = 0; kc < 4; kc++) {
        __syncthreads();
        for (int i = 0; i < 4; i++) {
            int gidx = i * 256 + t;
            int r = gidx >> 4, cg = gidx & 15;
            f32x4 wv4 = *(const f32x4*)&w_out[(size_t)(c0 + r) * 256 + kc * 64 + cg * 4];
            short4_t sv = { f2b(wv4[0]), f2b(wv4[1]), f2b(wv4[2]), f2b(wv4[3]) };
            *(short4_t*)&Ws[r][cg * 4] = sv;
        }
        for (int i = 0; i < 2; i++) {
            int idx = i * 256 + t;
            int r = idx >> 3, ch = idx & 7;
            *(short8*)&Os[r][ch * 8] = *(const short8*)&o_ws[((size_t)(b * NPOS) + p0 + r) * 256 + kc * 64 + ch * 8];
        }
        __syncthreads();
        for (int kk = 0; kk < 2; kk++) {
            short8 a = *(short8*)&Ws[wv * 16 + lr][kk * 32 + lg * 8];
            for (int fb = 0; fb < 4; fb++) {
                short8 ob = *(short8*)&Os[fb * 16 + lr][kk * 32 + lg * 8];
                acc[fb] = __builtin_amdgcn_mfma_f32_16x16x32_bf16(a, ob, acc[fb], 0, 0, 0);
            }
        }
    }
    for (int r = 0; r < 4; r++) {
        int c = c0 + wv * 16 + lg * 4 + r;
        float bias = b_out[c];
        for (int fb = 0; fb < 4; fb++) {
            float vv = acc[fb][r] + bias;
            out[((size_t)(b * CC) + c) * NPOS + p0 + fb * 16 + lr] = vv;   // f32 store
        }
    }
}

extern "C" void kernel_launch(void* const* d_in, const int* in_sizes, int n_in,
                              void* d_out, int out_size, void* d_ws, size_t ws_size,
                              hipStream_t stream) {
    const float* x     = (const float*)d_in[0];
    const float* g     = (const float*)d_in[1];
    const float* b     = (const float*)d_in[2];
    const float* w_qkv = (const float*)d_in[3];
    const float* w_out = (const float*)d_in[4];
    const float* b_out = (const float*)d_in[5];
    float* out = (float*)d_out;   // FLOAT32 output (verified R8)

    const size_t out_bytes = (size_t)out_size * sizeof(float);
    const size_t ws_need   = WS_TOTAL * sizeof(short);

    {   // Tripwire A: input ordering/sizes signature
        const int exp_sizes[6] = {655360, 128, 128, 98304, 32768, 128};
        int bad = -1;
        if (n_in != 6) bad = 15;
        else for (int i = 0; i < 6; i++) if (in_sizes[i] != exp_sizes[i]) { bad = i; break; }
        if (bad >= 0) { hipMemsetAsync(d_out, 0x50 | bad, out_bytes, stream); return; }
    }
    if (ws_size < ws_need) {   // Tripwire B: workspace size
        int mb = (int)(ws_size >> 20); if (mb > 15) mb = 15;
        hipMemsetAsync(d_out, 0x40 | mb, out_bytes, stream);
        return;
    }

    short* xn   = (short*)d_ws;
    short* q_ws = xn + XN_ELE;
    short* k_ws = q_ws + QKV_ELE;
    short* v_ws = k_ws + QKV_ELE;
    short* o_ws = v_ws + QKV_ELE;

    (void)hipGetLastError();
    ln_kernel<<<dim3(NPOS / 64, NB), 256, 0, stream>>>(x, g, b, xn);
    qkv_kernel<<<dim3(NPOS / 64, 12, NB), 256, 0, stream>>>(w_qkv, xn, q_ws, k_ws, v_ws);
    attn_kernel<<<dim3(NPOS / 64, NB * HEADS), 256, 0, stream>>>(q_ws, k_ws, v_ws, o_ws);
    proj_kernel<<<dim3(NPOS / 64, 2, NB), 256, 0, stream>>>(w_out, b_out, o_ws, out);
    if (hipGetLastError() != hipSuccess) {   // Tripwire C: launch failure flood
        hipMemsetAsync(d_out, 0xF0, out_bytes, stream);
    }
}

// Round 12
// 129.703 us; speedup vs baseline: 51.4835x; 1.0424x over previous
//
#include <hip/hip_runtime.h>
#include <hip/hip_bf16.h>

#define HEADS 4
#define DHEAD 64
#define CC 128
#define NPOS 2560
#define NB 2
#define NSPLIT 4
#define NT_SPLIT ((NPOS / 64) / NSPLIT)   // 10

// workspace (shorts): xn | q | k | v | o_ws | po[NSPLIT] | ml(float2)
#define XN_ELE  ((size_t)NB * NPOS * CC)             // 655360
#define QKV_ELE ((size_t)NB * HEADS * NPOS * DHEAD)  // 1310720
#define WS_BASE_BYTES  ((XN_ELE + 4 * QKV_ELE) * 2)                       // 11.25 MiB
#define WS_SPLIT_BYTES ((XN_ELE + (4 + NSPLIT) * QKV_ELE) * 2 \
                        + (size_t)NSPLIT * NB * HEADS * NPOS * 8)         // ~21.9 MiB

typedef __attribute__((ext_vector_type(8))) short short8;
typedef __attribute__((ext_vector_type(4))) short short4_t;
typedef __attribute__((ext_vector_type(4))) float f32x4;

// XOR-swizzled LDS index: 64-short (128B) rows, 16B-granule swizzle (T2).
#define SIDX(row, col) (((row) << 6) + ((col) ^ (((row) & 7) << 3)))

static __device__ __forceinline__ float b2f(short u) {
    union { unsigned int i; float f; } v;
    v.i = ((unsigned int)(unsigned short)u) << 16;
    return v.f;
}
static __device__ __forceinline__ short f2b(float f) {
    __hip_bfloat16 h = __float2bfloat16(f);
    union { __hip_bfloat16 h; unsigned short u; } v; v.h = h;
    return (short)v.u;
}

// -------- Kernel 1: channel LayerNorm (f32 in) -> xn transposed (b, pos, c) bf16 --------
__global__ __launch_bounds__(256) void ln_kernel(
    const float* __restrict__ x, const float* __restrict__ g,
    const float* __restrict__ bb, short* __restrict__ xn) {
    int p0 = blockIdx.x * 64, b = blockIdx.y;
    __shared__ float tile[128][65];
    __shared__ float redsum[4][64], redsq[4][64], meanS[64], invS[64];
    int t = threadIdx.x, p = t & 63, cpart = t >> 6;
    float s = 0.f, sq = 0.f;
    for (int k = 0; k < 32; k++) {
        int c = cpart * 32 + k;
        float v = x[((b * CC + c) * NPOS) + p0 + p];
        tile[c][p] = v;
        s += v; sq += v * v;
    }
    redsum[cpart][p] = s; redsq[cpart][p] = sq;
    __syncthreads();
    if (t < 64) {
        float S = redsum[0][t] + redsum[1][t] + redsum[2][t] + redsum[3][t];
        float Q = redsq[0][t] + redsq[1][t] + redsq[2][t] + redsq[3][t];
        float mean = S * (1.f / CC);
        float var = fmaxf(Q * (1.f / CC) - mean * mean, 0.f);
        meanS[t] = mean;
        invS[t] = 1.f / (sqrtf(var) + 1e-5f);
    }
    __syncthreads();
    for (int k = 0; k < 32; k++) {
        int idx = k * 256 + t;
        int c = idx & 127, pp = idx >> 7;
        float v = (tile[c][pp] - meanS[pp]) * invS[pp] * g[c] + bb[c];
        xn[((size_t)(b * NPOS) + p0 + pp) * CC + c] = f2b(v);
    }
}

// -------- Kernel 2: QKV projection (w f32). q:(bh,pos,d) scaled, k:(bh,pos,d), v:(bh,d,pos) --------
__global__ __launch_bounds__(256) void qkv_kernel(
    const float* __restrict__ w, const short* __restrict__ xn,
    short* __restrict__ q_ws, short* __restrict__ k_ws, short* __restrict__ v_ws) {
    int pt = blockIdx.x, ot = blockIdx.y, b = blockIdx.z;
    int p0 = pt * 64, o0 = ot * 64;
    __shared__ short Ws[64][136];
    __shared__ short Xs[64][136];
    int t = threadIdx.x, wv = t >> 6, l = t & 63;
    for (int i = 0; i < 8; i++) {
        int gidx = i * 256 + t;
        int r = gidx >> 5, cg = gidx & 31;
        f32x4 wv4 = *(const f32x4*)&w[(size_t)(o0 + r) * CC + cg * 4];
        short4_t sv = { f2b(wv4[0]), f2b(wv4[1]), f2b(wv4[2]), f2b(wv4[3]) };
        *(short4_t*)&Ws[r][cg * 4] = sv;
    }
    for (int i = 0; i < 4; i++) {
        int idx = i * 256 + t;
        int r = idx >> 4, ch = idx & 15;
        *(short8*)&Xs[r][ch * 8] = *(const short8*)&xn[((size_t)(b * NPOS) + p0 + r) * CC + ch * 8];
    }
    __syncthreads();
    f32x4 acc[4] = {{0,0,0,0},{0,0,0,0},{0,0,0,0},{0,0,0,0}};
    int lr = l & 15, lg = l >> 4;
    for (int kk = 0; kk < 4; kk++) {
        short8 a = *(short8*)&Ws[wv * 16 + lr][kk * 32 + lg * 8];
        for (int fb = 0; fb < 4; fb++) {
            short8 bf = *(short8*)&Xs[fb * 16 + lr][kk * 32 + lg * 8];
            acc[fb] = __builtin_amdgcn_mfma_f32_16x16x32_bf16(a, bf, acc[fb], 0, 0, 0);
        }
    }
    int orow0 = o0 + wv * 16 + lg * 4;
    int sec = orow0 >> 8;
    int oi = orow0 & 255, h = oi >> 6, d0 = oi & 63;
    size_t bh = (size_t)(b * HEADS + h);
    for (int fb = 0; fb < 4; fb++) {
        int pos = p0 + fb * 16 + lr;
        if (sec == 0) {
            short4_t qv = { f2b(acc[fb][0] * 0.125f), f2b(acc[fb][1] * 0.125f),
                            f2b(acc[fb][2] * 0.125f), f2b(acc[fb][3] * 0.125f) };
            *(short4_t*)&q_ws[(bh * NPOS + pos) * DHEAD + d0] = qv;
        } else if (sec == 1) {
            short4_t kv = { f2b(acc[fb][0]), f2b(acc[fb][1]), f2b(acc[fb][2]), f2b(acc[fb][3]) };
            *(short4_t*)&k_ws[(bh * NPOS + pos) * DHEAD + d0] = kv;
        } else {
            for (int r = 0; r < 4; r++)
                v_ws[(bh * DHEAD + d0 + r) * NPOS + pos] = f2b(acc[fb][r]);
        }
    }
}

// ======== flash-attention core (shared by split and non-split variants) ========
// Computes normalized O, m, l for KV tiles [kt0, kt0+nt). R11-proven math.
template <int NT>
static __device__ __forceinline__ void attn_core(
    const short* __restrict__ kbp, const short* __restrict__ vbp,
    const short8* qreg, int kt0,
    short* Ks0, short* Ks1, short* Vs0, short* Vs1, short* PsT,
    int t, float& m_, float& l_, f32x4* acc) {
    int wv = t >> 6, l = t & 63;
    int lr = l & 15, lg = l >> 4;
    int sr0 = t >> 3, sr1 = sr0 + 32, sc = (t & 7) * 8;
    int prow = wv * 16 + lr;
    short* KsA[2] = { Ks0, Ks1 };
    short* VsA[2] = { Vs0, Vs1 };

    // Prologue: stage first tile
    {
        int koff = kt0 * 64;
        *(short8*)&KsA[0][SIDX(sr0, sc)] = *(const short8*)&kbp[(size_t)(koff + sr0) * DHEAD + sc];
        *(short8*)&KsA[0][SIDX(sr1, sc)] = *(const short8*)&kbp[(size_t)(koff + sr1) * DHEAD + sc];
        *(short8*)&VsA[0][SIDX(sr0, sc)] = *(const short8*)&vbp[(size_t)sr0 * NPOS + koff + sc];
        *(short8*)&VsA[0][SIDX(sr1, sc)] = *(const short8*)&vbp[(size_t)sr1 * NPOS + koff + sc];
    }
    __syncthreads();

    for (int it = 0; it < NT; it++) {
        int cur = it & 1;
        bool pf = (it + 1 < NT);
        short8 kr0, kr1, vr0, vr1;
        if (pf) {
            int koff = (kt0 + it + 1) * 64;
            kr0 = *(const short8*)&kbp[(size_t)(koff + sr0) * DHEAD + sc];
            kr1 = *(const short8*)&kbp[(size_t)(koff + sr1) * DHEAD + sc];
            vr0 = *(const short8*)&vbp[(size_t)sr0 * NPOS + koff + sc];
            vr1 = *(const short8*)&vbp[(size_t)sr1 * NPOS + koff + sc];
        }
        f32x4 sf[4] = {{0,0,0,0},{0,0,0,0},{0,0,0,0},{0,0,0,0}};
        #pragma unroll
        for (int kk = 0; kk < 2; kk++) {
            #pragma unroll
            for (int fb = 0; fb < 4; fb++) {
                short8 kb = *(short8*)&KsA[cur][SIDX(fb * 16 + lr, kk * 32 + lg * 8)];
                sf[fb] = __builtin_amdgcn_mfma_f32_16x16x32_bf16(kb, qreg[kk], sf[fb], 0, 0, 0);
            }
        }
        float m0 = fmaxf(fmaxf(sf[0][0], sf[0][1]), fmaxf(sf[0][2], sf[0][3]));
        float m1 = fmaxf(fmaxf(sf[1][0], sf[1][1]), fmaxf(sf[1][2], sf[1][3]));
        float m2 = fmaxf(fmaxf(sf[2][0], sf[2][1]), fmaxf(sf[2][2], sf[2][3]));
        float m3 = fmaxf(fmaxf(sf[3][0], sf[3][1]), fmaxf(sf[3][2], sf[3][3]));
        float mx = fmaxf(fmaxf(m0, m1), fmaxf(m2, m3));
        mx = fmaxf(mx, __shfl_xor(mx, 16, 64));
        mx = fmaxf(mx, __shfl_xor(mx, 32, 64));
        float nm = fmaxf(m_, mx);
        float alpha = __expf(m_ - nm);
        float ps[4][4];
        float rs = 0.f;
        #pragma unroll
        for (int fb = 0; fb < 4; fb++) {
            float s0 = __expf(sf[fb][0] - nm), s1 = __expf(sf[fb][1] - nm);
            float s2 = __expf(sf[fb][2] - nm), s3 = __expf(sf[fb][3] - nm);
            ps[fb][0] = s0; ps[fb][1] = s1; ps[fb][2] = s2; ps[fb][3] = s3;
            rs += (s0 + s1) + (s2 + s3);
        }
        rs += __shfl_xor(rs, 16, 64);
        rs += __shfl_xor(rs, 32, 64);
        l_ = l_ * alpha + rs;
        m_ = nm;
        #pragma unroll
        for (int db = 0; db < 4; db++) {
            acc[db][0] *= alpha; acc[db][1] *= alpha;
            acc[db][2] *= alpha; acc[db][3] *= alpha;
        }
        #pragma unroll
        for (int fb = 0; fb < 4; fb++) {
            short4_t pk = { f2b(ps[fb][0]), f2b(ps[fb][1]), f2b(ps[fb][2]), f2b(ps[fb][3]) };
            *(short4_t*)&PsT[SIDX(prow, fb * 16 + lg * 4)] = pk;
        }
        #pragma unroll
        for (int kk = 0; kk < 2; kk++) {
            short8 pb = *(short8*)&PsT[SIDX(prow, kk * 32 + lg * 8)];
            #pragma unroll
            for (int db = 0; db < 4; db++) {
                short8 va = *(short8*)&VsA[cur][SIDX(db * 16 + lr, kk * 32 + lg * 8)];
                acc[db] = __builtin_amdgcn_mfma_f32_16x16x32_bf16(va, pb, acc[db], 0, 0, 0);
            }
        }
        if (pf) {
            *(short8*)&KsA[cur ^ 1][SIDX(sr0, sc)] = kr0;
            *(short8*)&KsA[cur ^ 1][SIDX(sr1, sc)] = kr1;
            *(short8*)&VsA[cur ^ 1][SIDX(sr0, sc)] = vr0;
            *(short8*)&VsA[cur ^ 1][SIDX(sr1, sc)] = vr1;
        }
        __syncthreads();
    }
}

// -------- Kernel 3a: full-KV attention (fallback; == R11, proven) --------
__global__ __launch_bounds__(256) void attn_kernel(
    const short* __restrict__ q_ws, const short* __restrict__ k_ws,
    const short* __restrict__ v_ws, short* __restrict__ o_ws) {
    int qt = blockIdx.x, bh = blockIdx.y;
    int q0 = qt * 64;
    __shared__ short Ks[2][64 * 64];
    __shared__ short Vs[2][64 * 64];
    __shared__ short PsT[64 * 64];
    int t = threadIdx.x, wv = t >> 6, l = t & 63;
    int lr = l & 15, lg = l >> 4;
    const short* kbp = k_ws + (size_t)bh * NPOS * DHEAD;
    const short* vbp = v_ws + (size_t)bh * DHEAD * NPOS;
    short8 qreg[2];
    for (int kk = 0; kk < 2; kk++)
        qreg[kk] = *(const short8*)&q_ws[((size_t)bh * NPOS + q0 + wv * 16 + lr) * DHEAD + kk * 32 + lg * 8];
    float m_ = -1e9f, l_ = 0.f;
    f32x4 acc[4] = {{0,0,0,0},{0,0,0,0},{0,0,0,0},{0,0,0,0}};
    attn_core<NPOS / 64>(kbp, vbp, qreg, 0, Ks[0], Ks[1], Vs[0], Vs[1], PsT, t, m_, l_, acc);
    int h = bh & (HEADS - 1), b = bh >> 2;
    float inv = 1.f / l_;
    int pos = q0 + wv * 16 + lr;
    #pragma unroll
    for (int db = 0; db < 4; db++) {
        short4_t ov = { f2b(acc[db][0] * inv), f2b(acc[db][1] * inv),
                        f2b(acc[db][2] * inv), f2b(acc[db][3] * inv) };
        *(short4_t*)&o_ws[((size_t)(b * NPOS) + pos) * 256 + h * DHEAD + db * 16 + lg * 4] = ov;
    }
}

// -------- Kernel 3b: split-KV attention -> po (normalized partial O) + ml (m,l) --------
__global__ __launch_bounds__(256) void attn_split_kernel(
    const short* __restrict__ q_ws, const short* __restrict__ k_ws,
    const short* __restrict__ v_ws, short* __restrict__ po, float* __restrict__ ml) {
    int qt = blockIdx.x, bh = blockIdx.y, s = blockIdx.z;
    int q0 = qt * 64;
    __shared__ short Ks[2][64 * 64];
    __shared__ short Vs[2][64 * 64];
    __shared__ short PsT[64 * 64];
    int t = threadIdx.x, wv = t >> 6, l = t & 63;
    int lr = l & 15, lg = l >> 4;
    const short* kbp = k_ws + (size_t)bh * NPOS * DHEAD;
    const short* vbp = v_ws + (size_t)bh * DHEAD * NPOS;
    short8 qreg[2];
    for (int kk = 0; kk < 2; kk++)
        qreg[kk] = *(const short8*)&q_ws[((size_t)bh * NPOS + q0 + wv * 16 + lr) * DHEAD + kk * 32 + lg * 8];
    float m_ = -1e9f, l_ = 0.f;
    f32x4 acc[4] = {{0,0,0,0},{0,0,0,0},{0,0,0,0},{0,0,0,0}};
    attn_core<NT_SPLIT>(kbp, vbp, qreg, s * NT_SPLIT, Ks[0], Ks[1], Vs[0], Vs[1], PsT, t, m_, l_, acc);
    float inv = 1.f / l_;
    int pos = q0 + wv * 16 + lr;
    size_t sb = (size_t)(s * NB * HEADS + bh);
    #pragma unroll
    for (int db = 0; db < 4; db++) {
        short4_t ov = { f2b(acc[db][0] * inv), f2b(acc[db][1] * inv),
                        f2b(acc[db][2] * inv), f2b(acc[db][3] * inv) };
        *(short4_t*)&po[(sb * NPOS + pos) * DHEAD + db * 16 + lg * 4] = ov;
    }
    if (lg == 0) {
        ml[2 * (sb * NPOS + pos) + 0] = m_;
        ml[2 * (sb * NPOS + pos) + 1] = l_;
    }
}

// -------- Kernel 3c: combine split partials -> o_ws (b, pos, h*64+d) --------
__global__ __launch_bounds__(256) void combine_kernel(
    const short* __restrict__ po, const float* __restrict__ ml, short* __restrict__ o_ws) {
    int tid = blockIdx.x * 256 + threadIdx.x;         // 0 .. NB*NPOS*32-1
    int c8 = tid & 31;                                // 32 chunks of 8 over 256 (h*64+d)
    int posb = tid >> 5;                              // b*NPOS + pos
    int b = posb / NPOS, pos = posb - b * NPOS;
    int h = c8 >> 3, d0 = (c8 & 7) * 8;
    int bh = b * HEADS + h;
    float ms[NSPLIT], ls[NSPLIT], m = -1e30f;
    #pragma unroll
    for (int s = 0; s < NSPLIT; s++) {
        size_t sb = (size_t)(s * NB * HEADS + bh);
        ms[s] = ml[2 * (sb * NPOS + pos) + 0];
        ls[s] = ml[2 * (sb * NPOS + pos) + 1];
        m = fmaxf(m, ms[s]);
    }
    float w[NSPLIT], wsum = 0.f;
    #pragma unroll
    for (int s = 0; s < NSPLIT; s++) { w[s] = ls[s] * __expf(ms[s] - m); wsum += w[s]; }
    float o8[8] = {0,0,0,0,0,0,0,0};
    #pragma unroll
    for (int s = 0; s < NSPLIT; s++) {
        size_t sb = (size_t)(s * NB * HEADS + bh);
        short8 v = *(const short8*)&po[(sb * NPOS + pos) * DHEAD + d0];
        #pragma unroll
        for (int j = 0; j < 8; j++) o8[j] += w[s] * b2f(v[j]);
    }
    float inv = 1.f / wsum;
    short8 ov;
    #pragma unroll
    for (int j = 0; j < 8; j++) ov[j] = f2b(o8[j] * inv);
    *(short8*)&o_ws[((size_t)posb) * 256 + h * DHEAD + d0] = ov;
}

// -------- Kernel 4: output projection, single-barrier full staging --------
__global__ __launch_bounds__(256) void proj_kernel(
    const float* __restrict__ w_out, const float* __restrict__ b_out,
    const short* __restrict__ o_ws, float* __restrict__ out) {
    int pt = blockIdx.x, ct = blockIdx.y, b = blockIdx.z;
    int p0 = pt * 64, c0 = ct * 64;
    __shared__ short Ws[64][264];   // 64 rows x 256 K, pad 8 -> conflict-free reads
    __shared__ short Os[64][264];
    int t = threadIdx.x, wv = t >> 6, l = t & 63;
    int lr = l & 15, lg = l >> 4;
    for (int i = 0; i < 16; i++) {            // W: 64x256 f32 -> bf16 (4096 f32x4)
        int gidx = i * 256 + t;
        int r = gidx >> 6, cg = gidx & 63;
        f32x4 wv4 = *(const f32x4*)&w_out[(size_t)(c0 + r) * 256 + cg * 4];
        short4_t sv = { f2b(wv4[0]), f2b(wv4[1]), f2b(wv4[2]), f2b(wv4[3]) };
        *(short4_t*)&Ws[r][cg * 4] = sv;
    }
    for (int i = 0; i < 8; i++) {             // O: 64x256 bf16 (2048 short8)
        int gidx = i * 256 + t;
        int r = gidx >> 5, ch = gidx & 31;
        *(short8*)&Os[r][ch * 8] = *(const short8*)&o_ws[((size_t)(b * NPOS) + p0 + r) * 256 + ch * 8];
    }
    __syncthreads();
    f32x4 acc[4] = {{0,0,0,0},{0,0,0,0},{0,0,0,0},{0,0,0,0}};
    for (int kc = 0; kc < 8; kc++) {          // 8 k-chunks of 32
        short8 a = *(short8*)&Ws[wv * 16 + lr][kc * 32 + lg * 8];
        #pragma unroll
        for (int fb = 0; fb < 4; fb++) {
            short8 ob = *(short8*)&Os[fb * 16 + lr][kc * 32 + lg * 8];
            acc[fb] = __builtin_amdgcn_mfma_f32_16x16x32_bf16(a, ob, acc[fb], 0, 0, 0);
        }
    }
    for (int r = 0; r < 4; r++) {
        int c = c0 + wv * 16 + lg * 4 + r;
        float bias = b_out[c];
        for (int fb = 0; fb < 4; fb++) {
            float vv = acc[fb][r] + bias;
            out[((size_t)(b * CC) + c) * NPOS + p0 + fb * 16 + lr] = vv;
        }
    }
}

extern "C" void kernel_launch(void* const* d_in, const int* in_sizes, int n_in,
                              void* d_out, int out_size, void* d_ws, size_t ws_size,
                              hipStream_t stream) {
    const float* x     = (const float*)d_in[0];
    const float* g     = (const float*)d_in[1];
    const float* b     = (const float*)d_in[2];
    const float* w_qkv = (const float*)d_in[3];
    const float* w_out = (const float*)d_in[4];
    const float* b_out = (const float*)d_in[5];
    float* out = (float*)d_out;   // FLOAT32 output (verified R8)

    const size_t out_bytes = (size_t)out_size * sizeof(float);

    {   // Tripwire A: input ordering/sizes signature
        const int exp_sizes[6] = {655360, 128, 128, 98304, 32768, 128};
        int bad = -1;
        if (n_in != 6) bad = 15;
        else for (int i = 0; i < 6; i++) if (in_sizes[i] != exp_sizes[i]) { bad = i; break; }
        if (bad >= 0) { hipMemsetAsync(d_out, 0x50 | bad, out_bytes, stream); return; }
    }
    if (ws_size < WS_BASE_BYTES) {   // Tripwire B: workspace size
        int mb = (int)(ws_size >> 20); if (mb > 15) mb = 15;
        hipMemsetAsync(d_out, 0x40 | mb, out_bytes, stream);
        return;
    }

    short* xn   = (short*)d_ws;
    short* q_ws = xn + XN_ELE;
    short* k_ws = q_ws + QKV_ELE;
    short* v_ws = k_ws + QKV_ELE;
    short* o_ws = v_ws + QKV_ELE;
    short* po   = o_ws + QKV_ELE;                       // NSPLIT x QKV_ELE
    float* ml   = (float*)(po + NSPLIT * QKV_ELE);      // NSPLIT x NB*HEADS*NPOS x float2

    const bool use_split = (ws_size >= WS_SPLIT_BYTES);

    (void)hipGetLastError();
    ln_kernel<<<dim3(NPOS / 64, NB), 256, 0, stream>>>(x, g, b, xn);
    qkv_kernel<<<dim3(NPOS / 64, 12, NB), 256, 0, stream>>>(w_qkv, xn, q_ws, k_ws, v_ws);
    if (use_split) {
        attn_split_kernel<<<dim3(NPOS / 64, NB * HEADS, NSPLIT), 256, 0, stream>>>(q_ws, k_ws, v_ws, po, ml);
        combine_kernel<<<dim3(NB * NPOS * 32 / 256), 256, 0, stream>>>(po, ml, o_ws);
    } else {
        attn_kernel<<<dim3(NPOS / 64, NB * HEADS), 256, 0, stream>>>(q_ws, k_ws, v_ws, o_ws);
    }
    proj_kernel<<<dim3(NPOS / 64, 2, NB), 256, 0, stream>>>(w_out, b_out, o_ws, out);
    if (hipGetLastError() != hipSuccess) {   // Tripwire C: launch failure flood
        hipMemsetAsync(d_out, 0xF0, out_bytes, stream);
    }
}

// Round 13
// 111.813 us; speedup vs baseline: 59.7207x; 1.1600x over previous
//
#include <hip/hip_runtime.h>
#include <hip/hip_bf16.h>

#define HEADS 4
#define DHEAD 64
#define CC 128
#define NPOS 2560
#define NB 2
#define NSPLIT 4
#define NT_SPLIT ((NPOS / 64) / NSPLIT)   // 10

// workspace (shorts): xn | q | k | v | o_ws | po[NSPLIT] | ml(float2)
#define XN_ELE  ((size_t)NB * NPOS * CC)             // 655360
#define QKV_ELE ((size_t)NB * HEADS * NPOS * DHEAD)  // 1310720
#define WS_BASE_BYTES  ((XN_ELE + 4 * QKV_ELE) * 2)                       // 11.25 MiB
#define WS_SPLIT_BYTES ((XN_ELE + (4 + NSPLIT) * QKV_ELE) * 2 \
                        + (size_t)NSPLIT * NB * HEADS * NPOS * 8)         // ~21.9 MiB

typedef __attribute__((ext_vector_type(8))) short short8;
typedef __attribute__((ext_vector_type(4))) short short4_t;
typedef __attribute__((ext_vector_type(4))) float f32x4;

// XOR-swizzled LDS index: 64-short (128B) rows, 16B-granule swizzle (T2).
#define SIDX(row, col) (((row) << 6) + ((col) ^ (((row) & 7) << 3)))

static __device__ __forceinline__ float b2f(short u) {
    union { unsigned int i; float f; } v;
    v.i = ((unsigned int)(unsigned short)u) << 16;
    return v.f;
}
static __device__ __forceinline__ short f2b(float f) {
    __hip_bfloat16 h = __float2bfloat16(f);
    union { __hip_bfloat16 h; unsigned short u; } v; v.h = h;
    return (short)v.u;
}

// -------- Kernel 1: channel LayerNorm (f32 in) -> xn transposed (b, pos, c) bf16 --------
__global__ __launch_bounds__(256) void ln_kernel(
    const float* __restrict__ x, const float* __restrict__ g,
    const float* __restrict__ bb, short* __restrict__ xn) {
    int p0 = blockIdx.x * 64, b = blockIdx.y;
    __shared__ float tile[128][65];
    __shared__ float redsum[4][64], redsq[4][64], meanS[64], invS[64];
    int t = threadIdx.x, p = t & 63, cpart = t >> 6;
    float s = 0.f, sq = 0.f;
    for (int k = 0; k < 32; k++) {
        int c = cpart * 32 + k;
        float v = x[((b * CC + c) * NPOS) + p0 + p];
        tile[c][p] = v;
        s += v; sq += v * v;
    }
    redsum[cpart][p] = s; redsq[cpart][p] = sq;
    __syncthreads();
    if (t < 64) {
        float S = redsum[0][t] + redsum[1][t] + redsum[2][t] + redsum[3][t];
        float Q = redsq[0][t] + redsq[1][t] + redsq[2][t] + redsq[3][t];
        float mean = S * (1.f / CC);
        float var = fmaxf(Q * (1.f / CC) - mean * mean, 0.f);
        meanS[t] = mean;
        invS[t] = 1.f / (sqrtf(var) + 1e-5f);
    }
    __syncthreads();
    for (int k = 0; k < 32; k++) {
        int idx = k * 256 + t;
        int c = idx & 127, pp = idx >> 7;
        float v = (tile[c][pp] - meanS[pp]) * invS[pp] * g[c] + bb[c];
        xn[((size_t)(b * NPOS) + p0 + pp) * CC + c] = f2b(v);
    }
}

// -------- Kernel 2: QKV projection (w f32). q:(bh,pos,d) scaled, k:(bh,pos,d), v:(bh,d,pos) --------
__global__ __launch_bounds__(256) void qkv_kernel(
    const float* __restrict__ w, const short* __restrict__ xn,
    short* __restrict__ q_ws, short* __restrict__ k_ws, short* __restrict__ v_ws) {
    int pt = blockIdx.x, ot = blockIdx.y, b = blockIdx.z;
    int p0 = pt * 64, o0 = ot * 64;
    __shared__ short Ws[64][136];
    __shared__ short Xs[64][136];
    int t = threadIdx.x, wv = t >> 6, l = t & 63;
    for (int i = 0; i < 8; i++) {
        int gidx = i * 256 + t;
        int r = gidx >> 5, cg = gidx & 31;
        f32x4 wv4 = *(const f32x4*)&w[(size_t)(o0 + r) * CC + cg * 4];
        short4_t sv = { f2b(wv4[0]), f2b(wv4[1]), f2b(wv4[2]), f2b(wv4[3]) };
        *(short4_t*)&Ws[r][cg * 4] = sv;
    }
    for (int i = 0; i < 4; i++) {
        int idx = i * 256 + t;
        int r = idx >> 4, ch = idx & 15;
        *(short8*)&Xs[r][ch * 8] = *(const short8*)&xn[((size_t)(b * NPOS) + p0 + r) * CC + ch * 8];
    }
    __syncthreads();
    f32x4 acc[4] = {{0,0,0,0},{0,0,0,0},{0,0,0,0},{0,0,0,0}};
    int lr = l & 15, lg = l >> 4;
    for (int kk = 0; kk < 4; kk++) {
        short8 a = *(short8*)&Ws[wv * 16 + lr][kk * 32 + lg * 8];
        for (int fb = 0; fb < 4; fb++) {
            short8 bf = *(short8*)&Xs[fb * 16 + lr][kk * 32 + lg * 8];
            acc[fb] = __builtin_amdgcn_mfma_f32_16x16x32_bf16(a, bf, acc[fb], 0, 0, 0);
        }
    }
    int orow0 = o0 + wv * 16 + lg * 4;
    int sec = orow0 >> 8;
    int oi = orow0 & 255, h = oi >> 6, d0 = oi & 63;
    size_t bh = (size_t)(b * HEADS + h);
    for (int fb = 0; fb < 4; fb++) {
        int pos = p0 + fb * 16 + lr;
        if (sec == 0) {
            short4_t qv = { f2b(acc[fb][0] * 0.125f), f2b(acc[fb][1] * 0.125f),
                            f2b(acc[fb][2] * 0.125f), f2b(acc[fb][3] * 0.125f) };
            *(short4_t*)&q_ws[(bh * NPOS + pos) * DHEAD + d0] = qv;
        } else if (sec == 1) {
            short4_t kv = { f2b(acc[fb][0]), f2b(acc[fb][1]), f2b(acc[fb][2]), f2b(acc[fb][3]) };
            *(short4_t*)&k_ws[(bh * NPOS + pos) * DHEAD + d0] = kv;
        } else {
            for (int r = 0; r < 4; r++)
                v_ws[(bh * DHEAD + d0 + r) * NPOS + pos] = f2b(acc[fb][r]);
        }
    }
}

// ======== flash-attention core: single-buffered K/V, async-stage split (T14), ========
// ======== defer-max (T13, THR=8). LDS = 24 KB -> 6 blocks/CU.                 ========
template <int NT>
static __device__ __forceinline__ void attn_core(
    const short* __restrict__ kbp, const short* __restrict__ vbp,
    const short8* qreg, int kt0,
    short* Ks, short* Vs, short* PsT,
    int t, float& m_, float& l_, f32x4* acc) {
    int wv = t >> 6, l = t & 63;
    int lr = l & 15, lg = l >> 4;
    int sr0 = t >> 3, sr1 = sr0 + 32, sc = (t & 7) * 8;
    int prow = wv * 16 + lr;

    {   // prologue: stage first tile
        int koff = kt0 * 64;
        *(short8*)&Ks[SIDX(sr0, sc)] = *(const short8*)&kbp[(size_t)(koff + sr0) * DHEAD + sc];
        *(short8*)&Ks[SIDX(sr1, sc)] = *(const short8*)&kbp[(size_t)(koff + sr1) * DHEAD + sc];
        *(short8*)&Vs[SIDX(sr0, sc)] = *(const short8*)&vbp[(size_t)sr0 * NPOS + koff + sc];
        *(short8*)&Vs[SIDX(sr1, sc)] = *(const short8*)&vbp[(size_t)sr1 * NPOS + koff + sc];
    }
    __syncthreads();

    for (int it = 0; it < NT; it++) {
        bool pf = (it + 1 < NT);
        short8 kr0, kr1, vr0, vr1;
        if (pf) {   // issue next tile's loads early; latency hides under compute
            int koff = (kt0 + it + 1) * 64;
            kr0 = *(const short8*)&kbp[(size_t)(koff + sr0) * DHEAD + sc];
            kr1 = *(const short8*)&kbp[(size_t)(koff + sr1) * DHEAD + sc];
            vr0 = *(const short8*)&vbp[(size_t)sr0 * NPOS + koff + sc];
            vr1 = *(const short8*)&vbp[(size_t)sr1 * NPOS + koff + sc];
        }
        // QK^T (swapped): sf[fb][r] = S^T[k=fb*16+lg*4+r][q=prow]
        f32x4 sf[4] = {{0,0,0,0},{0,0,0,0},{0,0,0,0},{0,0,0,0}};
        #pragma unroll
        for (int kk = 0; kk < 2; kk++) {
            #pragma unroll
            for (int fb = 0; fb < 4; fb++) {
                short8 kb = *(short8*)&Ks[SIDX(fb * 16 + lr, kk * 32 + lg * 8)];
                sf[fb] = __builtin_amdgcn_mfma_f32_16x16x32_bf16(kb, qreg[kk], sf[fb], 0, 0, 0);
            }
        }
        // row max (in-lane + 2 shuffles)
        float m0 = fmaxf(fmaxf(sf[0][0], sf[0][1]), fmaxf(sf[0][2], sf[0][3]));
        float m1 = fmaxf(fmaxf(sf[1][0], sf[1][1]), fmaxf(sf[1][2], sf[1][3]));
        float m2 = fmaxf(fmaxf(sf[2][0], sf[2][1]), fmaxf(sf[2][2], sf[2][3]));
        float m3 = fmaxf(fmaxf(sf[3][0], sf[3][1]), fmaxf(sf[3][2], sf[3][3]));
        float mx = fmaxf(fmaxf(m0, m1), fmaxf(m2, m3));
        mx = fmaxf(mx, __shfl_xor(mx, 16, 64));
        mx = fmaxf(mx, __shfl_xor(mx, 32, 64));
        // defer-max (T13): only rescale when max grew by > 8 (P bounded by e^8)
        if (!__all(mx - m_ <= 8.0f)) {
            float nm = fmaxf(m_, mx);
            float alpha = __expf(m_ - nm);
            l_ *= alpha;
            #pragma unroll
            for (int db = 0; db < 4; db++) {
                acc[db][0] *= alpha; acc[db][1] *= alpha;
                acc[db][2] *= alpha; acc[db][3] *= alpha;
            }
            m_ = nm;
        }
        float ps[4][4];
        float rs = 0.f;
        #pragma unroll
        for (int fb = 0; fb < 4; fb++) {
            float s0 = __expf(sf[fb][0] - m_), s1 = __expf(sf[fb][1] - m_);
            float s2 = __expf(sf[fb][2] - m_), s3 = __expf(sf[fb][3] - m_);
            ps[fb][0] = s0; ps[fb][1] = s1; ps[fb][2] = s2; ps[fb][3] = s3;
            rs += (s0 + s1) + (s2 + s3);
        }
        rs += __shfl_xor(rs, 16, 64);
        rs += __shfl_xor(rs, 32, 64);
        l_ += rs;
        // P^T rows (wave-private)
        #pragma unroll
        for (int fb = 0; fb < 4; fb++) {
            short4_t pk = { f2b(ps[fb][0]), f2b(ps[fb][1]), f2b(ps[fb][2]), f2b(ps[fb][3]) };
            *(short4_t*)&PsT[SIDX(prow, fb * 16 + lg * 4)] = pk;
        }
        // PV
        #pragma unroll
        for (int kk = 0; kk < 2; kk++) {
            short8 pb = *(short8*)&PsT[SIDX(prow, kk * 32 + lg * 8)];
            #pragma unroll
            for (int db = 0; db < 4; db++) {
                short8 va = *(short8*)&Vs[SIDX(db * 16 + lr, kk * 32 + lg * 8)];
                acc[db] = __builtin_amdgcn_mfma_f32_16x16x32_bf16(va, pb, acc[db], 0, 0, 0);
            }
        }
        if (pf) {   // land prefetched tile into the (single) buffer
            __syncthreads();   // all waves done reading K/V
            *(short8*)&Ks[SIDX(sr0, sc)] = kr0;
            *(short8*)&Ks[SIDX(sr1, sc)] = kr1;
            *(short8*)&Vs[SIDX(sr0, sc)] = vr0;
            *(short8*)&Vs[SIDX(sr1, sc)] = vr1;
            __syncthreads();   // writes visible
        }
    }
}

// -------- Kernel 3a: full-KV attention (fallback) --------
__global__ __launch_bounds__(256) void attn_kernel(
    const short* __restrict__ q_ws, const short* __restrict__ k_ws,
    const short* __restrict__ v_ws, short* __restrict__ o_ws) {
    int qt = blockIdx.x, bh = blockIdx.y;
    int q0 = qt * 64;
    __shared__ short Ks[64 * 64];
    __shared__ short Vs[64 * 64];
    __shared__ short PsT[64 * 64];
    int t = threadIdx.x, wv = t >> 6, l = t & 63;
    int lr = l & 15, lg = l >> 4;
    const short* kbp = k_ws + (size_t)bh * NPOS * DHEAD;
    const short* vbp = v_ws + (size_t)bh * DHEAD * NPOS;
    short8 qreg[2];
    for (int kk = 0; kk < 2; kk++)
        qreg[kk] = *(const short8*)&q_ws[((size_t)bh * NPOS + q0 + wv * 16 + lr) * DHEAD + kk * 32 + lg * 8];
    float m_ = -1e9f, l_ = 0.f;
    f32x4 acc[4] = {{0,0,0,0},{0,0,0,0},{0,0,0,0},{0,0,0,0}};
    attn_core<NPOS / 64>(kbp, vbp, qreg, 0, Ks, Vs, PsT, t, m_, l_, acc);
    int h = bh & (HEADS - 1), b = bh >> 2;
    float inv = 1.f / l_;
    int pos = q0 + wv * 16 + lr;
    #pragma unroll
    for (int db = 0; db < 4; db++) {
        short4_t ov = { f2b(acc[db][0] * inv), f2b(acc[db][1] * inv),
                        f2b(acc[db][2] * inv), f2b(acc[db][3] * inv) };
        *(short4_t*)&o_ws[((size_t)(b * NPOS) + pos) * 256 + h * DHEAD + db * 16 + lg * 4] = ov;
    }
}

// -------- Kernel 3b: split-KV attention -> po (normalized partial O) + ml (m,l) --------
__global__ __launch_bounds__(256) void attn_split_kernel(
    const short* __restrict__ q_ws, const short* __restrict__ k_ws,
    const short* __restrict__ v_ws, short* __restrict__ po, float* __restrict__ ml) {
    int qt = blockIdx.x, bh = blockIdx.y, s = blockIdx.z;
    int q0 = qt * 64;
    __shared__ short Ks[64 * 64];
    __shared__ short Vs[64 * 64];
    __shared__ short PsT[64 * 64];
    int t = threadIdx.x, wv = t >> 6, l = t & 63;
    int lr = l & 15, lg = l >> 4;
    const short* kbp = k_ws + (size_t)bh * NPOS * DHEAD;
    const short* vbp = v_ws + (size_t)bh * DHEAD * NPOS;
    short8 qreg[2];
    for (int kk = 0; kk < 2; kk++)
        qreg[kk] = *(const short8*)&q_ws[((size_t)bh * NPOS + q0 + wv * 16 + lr) * DHEAD + kk * 32 + lg * 8];
    float m_ = -1e9f, l_ = 0.f;
    f32x4 acc[4] = {{0,0,0,0},{0,0,0,0},{0,0,0,0},{0,0,0,0}};
    attn_core<NT_SPLIT>(kbp, vbp, qreg, s * NT_SPLIT, Ks, Vs, PsT, t, m_, l_, acc);
    float inv = 1.f / l_;
    int pos = q0 + wv * 16 + lr;
    size_t sb = (size_t)(s * NB * HEADS + bh);
    #pragma unroll
    for (int db = 0; db < 4; db++) {
        short4_t ov = { f2b(acc[db][0] * inv), f2b(acc[db][1] * inv),
                        f2b(acc[db][2] * inv), f2b(acc[db][3] * inv) };
        *(short4_t*)&po[(sb * NPOS + pos) * DHEAD + db * 16 + lg * 4] = ov;
    }
    if (lg == 0) {
        ml[2 * (sb * NPOS + pos) + 0] = m_;
        ml[2 * (sb * NPOS + pos) + 1] = l_;
    }
}

// -------- Kernel 4: output projection; SPLIT=true fuses the split-combine --------
template <bool SPLIT>
__global__ __launch_bounds__(256) void proj_kernel(
    const float* __restrict__ w_out, const float* __restrict__ b_out,
    const short* __restrict__ o_ws, const short* __restrict__ po,
    const float* __restrict__ ml, float* __restrict__ out) {
    int pt = blockIdx.x, ct = blockIdx.y, b = blockIdx.z;
    int p0 = pt * 64, c0 = ct * 64;
    __shared__ short Ws[64][264];
    __shared__ short Os[64][264];
    int t = threadIdx.x, wv = t >> 6, l = t & 63;
    int lr = l & 15, lg = l >> 4;
    for (int i = 0; i < 16; i++) {            // W: 64x256 f32 -> bf16
        int gidx = i * 256 + t;
        int r = gidx >> 6, cg = gidx & 63;
        f32x4 wv4 = *(const f32x4*)&w_out[(size_t)(c0 + r) * 256 + cg * 4];
        short4_t sv = { f2b(wv4[0]), f2b(wv4[1]), f2b(wv4[2]), f2b(wv4[3]) };
        *(short4_t*)&Ws[r][cg * 4] = sv;
    }
    for (int i = 0; i < 8; i++) {             // O: 64x256, combined inline when SPLIT
        int gidx = i * 256 + t;
        int r = gidx >> 5, ch = gidx & 31;
        if constexpr (SPLIT) {
            int pos = p0 + r;
            int h = ch >> 3, d0 = (ch & 7) * 8;
            int bh = b * HEADS + h;
            float ms[NSPLIT], ls[NSPLIT], m = -1e30f;
            #pragma unroll
            for (int s = 0; s < NSPLIT; s++) {
                size_t sb = (size_t)(s * NB * HEADS + bh);
                ms[s] = ml[2 * (sb * NPOS + pos) + 0];
                ls[s] = ml[2 * (sb * NPOS + pos) + 1];
                m = fmaxf(m, ms[s]);
            }
            float w4[NSPLIT], wsum = 0.f;
            #pragma unroll
            for (int s = 0; s < NSPLIT; s++) { w4[s] = ls[s] * __expf(ms[s] - m); wsum += w4[s]; }
            float o8[8] = {0,0,0,0,0,0,0,0};
            #pragma unroll
            for (int s = 0; s < NSPLIT; s++) {
                size_t sb = (size_t)(s * NB * HEADS + bh);
                short8 v = *(const short8*)&po[(sb * NPOS + pos) * DHEAD + d0];
                #pragma unroll
                for (int j = 0; j < 8; j++) o8[j] += w4[s] * b2f(v[j]);
            }
            float invw = 1.f / wsum;
            short8 ov;
            #pragma unroll
            for (int j = 0; j < 8; j++) ov[j] = f2b(o8[j] * invw);
            *(short8*)&Os[r][ch * 8] = ov;
        } else {
            *(short8*)&Os[r][ch * 8] = *(const short8*)&o_ws[((size_t)(b * NPOS) + p0 + r) * 256 + ch * 8];
        }
    }
    __syncthreads();
    f32x4 acc[4] = {{0,0,0,0},{0,0,0,0},{0,0,0,0},{0,0,0,0}};
    for (int kc = 0; kc < 8; kc++) {
        short8 a = *(short8*)&Ws[wv * 16 + lr][kc * 32 + lg * 8];
        #pragma unroll
        for (int fb = 0; fb < 4; fb++) {
            short8 ob = *(short8*)&Os[fb * 16 + lr][kc * 32 + lg * 8];
            acc[fb] = __builtin_amdgcn_mfma_f32_16x16x32_bf16(a, ob, acc[fb], 0, 0, 0);
        }
    }
    for (int r = 0; r < 4; r++) {
        int c = c0 + wv * 16 + lg * 4 + r;
        float bias = b_out[c];
        for (int fb = 0; fb < 4; fb++) {
            float vv = acc[fb][r] + bias;
            out[((size_t)(b * CC) + c) * NPOS + p0 + fb * 16 + lr] = vv;
        }
    }
}

extern "C" void kernel_launch(void* const* d_in, const int* in_sizes, int n_in,
                              void* d_out, int out_size, void* d_ws, size_t ws_size,
                              hipStream_t stream) {
    const float* x     = (const float*)d_in[0];
    const float* g     = (const float*)d_in[1];
    const float* b     = (const float*)d_in[2];
    const float* w_qkv = (const float*)d_in[3];
    const float* w_out = (const float*)d_in[4];
    const float* b_out = (const float*)d_in[5];
    float* out = (float*)d_out;   // FLOAT32 output (verified R8)

    const size_t out_bytes = (size_t)out_size * sizeof(float);

    {   // Tripwire A: input ordering/sizes signature
        const int exp_sizes[6] = {655360, 128, 128, 98304, 32768, 128};
        int bad = -1;
        if (n_in != 6) bad = 15;
        else for (int i = 0; i < 6; i++) if (in_sizes[i] != exp_sizes[i]) { bad = i; break; }
        if (bad >= 0) { hipMemsetAsync(d_out, 0x50 | bad, out_bytes, stream); return; }
    }
    if (ws_size < WS_BASE_BYTES) {   // Tripwire B: workspace size
        int mb = (int)(ws_size >> 20); if (mb > 15) mb = 15;
        hipMemsetAsync(d_out, 0x40 | mb, out_bytes, stream);
        return;
    }

    short* xn   = (short*)d_ws;
    short* q_ws = xn + XN_ELE;
    short* k_ws = q_ws + QKV_ELE;
    short* v_ws = k_ws + QKV_ELE;
    short* o_ws = v_ws + QKV_ELE;
    short* po   = o_ws + QKV_ELE;                       // NSPLIT x QKV_ELE
    float* ml   = (float*)(po + NSPLIT * QKV_ELE);      // NSPLIT x NB*HEADS*NPOS x float2

    const bool use_split = (ws_size >= WS_SPLIT_BYTES);

    (void)hipGetLastError();
    ln_kernel<<<dim3(NPOS / 64, NB), 256, 0, stream>>>(x, g, b, xn);
    qkv_kernel<<<dim3(NPOS / 64, 12, NB), 256, 0, stream>>>(w_qkv, xn, q_ws, k_ws, v_ws);
    if (use_split) {
        attn_split_kernel<<<dim3(NPOS / 64, NB * HEADS, NSPLIT), 256, 0, stream>>>(q_ws, k_ws, v_ws, po, ml);
        proj_kernel<true><<<dim3(NPOS / 64, 2, NB), 256, 0, stream>>>(w_out, b_out, o_ws, po, ml, out);
    } else {
        attn_kernel<<<dim3(NPOS / 64, NB * HEADS), 256, 0, stream>>>(q_ws, k_ws, v_ws, o_ws);
        proj_kernel<false><<<dim3(NPOS / 64, 2, NB), 256, 0, stream>>>(w_out, b_out, o_ws, po, ml, out);
    }
    if (hipGetLastError() != hipSuccess) {   // Tripwire C: launch failure flood
        hipMemsetAsync(d_out, 0xF0, out_bytes, stream);
    }
}